// Round 2
// baseline (206.034 us; speedup 1.0000x reference)
//
#include <hip/hip_runtime.h>
#include <stdint.h>

#define NB     65536
#define BATCH  4
#define TOPN   1000
#define MMAX   2048
#define NTILE  (MMAX / 64)                 // 32
#define NPAIRS (NTILE * (NTILE + 1) / 2)   // 528
#define CAP    128                         // per-prep-block candidate region
#define KSUP   8
#define UNC    128
#define THRESH 0.974f
#define NEGV   (-1e9f)
#define NMS_T  0.7f
#define GRIDN  256                         // fused-kernel grid size (1 block/CU)

// ws layout (bytes) — unchanged from the 4-kernel version:
//   ctrs u32[16]: [0..3]=n, [8..11]=fallback flag, [12]=bar_count, [13]=bar_gen
#define OFF_CBLK   64
#define OFF_KRAW   1088
#define OFF_SBOX   263232
#define OFF_SLEV   394304
#define OFF_CNT2   427072
#define OFF_SUP    459840

__device__ __forceinline__ void decode_box(const float4* __restrict__ anchors4,
                                           const float4* __restrict__ deltas4,
                                           int b, int i, float wmax, float hmax,
                                           float& x1, float& y1, float& x2, float& y2) {
  float4 a = anchors4[i];
  float4 d = deltas4[(size_t)b * NB + i];
  float ws = a.z - a.x + 1.0f;
  float hs = a.w - a.y + 1.0f;
  float cx = a.x + 0.5f * ws;
  float cy = a.y + 0.5f * hs;
  float pcx = d.x * ws + cx;
  float pcy = d.y * hs + cy;
  float pw = expf(d.z) * ws;
  float ph = expf(d.w) * hs;
  x1 = pcx - 0.5f * pw; y1 = pcy - 0.5f * ph;
  x2 = pcx + 0.5f * pw; y2 = pcy + 0.5f * ph;
  x1 = fminf(fmaxf(x1, 0.0f), wmax);
  y1 = fminf(fmaxf(y1, 0.0f), hmax);
  x2 = fminf(fmaxf(x2, 0.0f), wmax);
  y2 = fminf(fmaxf(y2, 0.0f), hmax);
}

// block-wide exclusive scan, 256 threads (4 waves). wsum: u32[5].
__device__ __forceinline__ uint32_t blockscan(uint32_t v, volatile uint32_t* wsum,
                                              int tid, uint32_t* total) {
  __syncthreads();
  int lane = tid & 63, wid = tid >> 6;
  uint32_t x = v;
  for (int off = 1; off < 64; off <<= 1) {
    uint32_t u = __shfl_up(x, off, 64);
    if (lane >= off) x += u;
  }
  if (lane == 63) wsum[wid] = x;
  __syncthreads();
  if (tid == 0) {
    uint32_t run = 0;
    for (int w = 0; w < 4; ++w) { uint32_t t = wsum[w]; wsum[w] = run; run += t; }
    wsum[4] = run;
  }
  __syncthreads();
  *total = wsum[4];
  return x - v + wsum[wid];
}

// Hand-rolled grid barrier. Safe because grid(256) <= CU count(256) and
// occupancy >= 1 block/CU, so all blocks are co-resident under any packing.
// Agent-scope acq-rel atomics publish prior plain stores across XCDs.
// Self-restoring: count ends at 0, gen increases monotonically (replay-safe).
__device__ __forceinline__ void gbar(uint32_t* cnt, uint32_t* gen, int tid) {
  __syncthreads();
  if (tid == 0) {
    __threadfence();  // release prior writes device-wide
    uint32_t g = __hip_atomic_load(gen, __ATOMIC_RELAXED, __HIP_MEMORY_SCOPE_AGENT);
    uint32_t a = __hip_atomic_fetch_add(cnt, 1u, __ATOMIC_ACQ_REL, __HIP_MEMORY_SCOPE_AGENT);
    if (a == (uint32_t)(GRIDN - 1)) {
      __hip_atomic_store(cnt, 0u, __ATOMIC_RELAXED, __HIP_MEMORY_SCOPE_AGENT);
      __hip_atomic_fetch_add(gen, 1u, __ATOMIC_RELEASE, __HIP_MEMORY_SCOPE_AGENT);
    } else {
      while (__hip_atomic_load(gen, __ATOMIC_ACQUIRE, __HIP_MEMORY_SCOPE_AGENT) == g)
        __builtin_amdgcn_s_sleep(2);
    }
    __threadfence();  // acquire side
  }
  __syncthreads();
}

__global__ void k_init(uint32_t* ctrs) {
  if (threadIdx.x < 2)
    __hip_atomic_store(&ctrs[12 + threadIdx.x], 0u, __ATOMIC_RELAXED,
                       __HIP_MEMORY_SCOPE_AGENT);
}

// Fused pipeline: prep -> rank -> pairs -> out, separated by hand-rolled
// grid barriers. 256 blocks x 256 threads = 1 block/CU.
__global__ __launch_bounds__(256) void k_fused(
    const float* __restrict__ scores, const float4* __restrict__ deltas4,
    const float4* __restrict__ anchors4, const float* __restrict__ im_info,
    const int* __restrict__ ids,
    unsigned long long* __restrict__ keys_raw, uint32_t* __restrict__ cnt_blk,
    uint32_t* ctrs, float4* __restrict__ sboxes, int* __restrict__ slev,
    uint32_t* __restrict__ cnt2, int* __restrict__ suplist,
    float* __restrict__ out) {
  const int bid = blockIdx.x;
  const int tid = threadIdx.x;
  const int lane = tid & 63, wid = tid >> 6;
  uint32_t* bar_cnt = &ctrs[12];
  uint32_t* bar_gen = &ctrs[13];

  // ---- shared memory (static; lifetimes separated by grid barriers) ----
  __shared__ uint32_t wsum[17];                 // P1 + P4 scans (uses [0..4])
  __shared__ unsigned long long sk[MMAX];       // P2: 16 KB
  __shared__ uint32_t scnt[64], sbs[64];        // P2
  __shared__ uint32_t psum[256];                // P2
  __shared__ uint32_t meta[2];                  // P2
  __shared__ uint8_t  kept[MMAX];               // P4
  __shared__ uint16_t unc[UNC];                 // P4
  __shared__ int      supld[UNC][KSUP];         // P4: 4 KB
  __shared__ uint8_t  supn[UNC];                // P4
  __shared__ uint32_t mask[NB / 32];            // P4 fallback: 8 KB
  __shared__ float    rv[256];                  // P4 fallback
  __shared__ int      ri[256];                  // P4 fallback
  __shared__ float    fm[4];                    // P4 fallback

  // ================= P1: score-threshold scan (all 256 blocks) =================
  {
    const int b = bid >> 6;        // 64 blocks / image
    const int blk = bid & 63;      // 1024 scores / block
    const float4* s4 = (const float4*)scores + (size_t)b * (NB / 4) + (size_t)blk * 256 + tid;
    float4 s = *s4;
    float sc4[4] = {s.x, s.y, s.z, s.w};
    uint32_t cmask = 0, ccount = 0;
#pragma unroll
    for (int k = 0; k < 4; ++k)
      if (sc4[k] >= THRESH) { cmask |= (1u << k); ccount++; }
    uint32_t total;
    uint32_t p = blockscan(ccount, wsum, tid, &total);
    if (tid == 0) cnt_blk[bid] = total;  // TRUE count (P2 detects >CAP)
    unsigned long long* dst = keys_raw + (size_t)bid * CAP;
#pragma unroll
    for (int k = 0; k < 4; ++k) {
      if (cmask & (1u << k)) {
        if (p < (uint32_t)CAP) {
          int i = (blk << 10) + (tid << 2) + k;
          dst[p] = ((unsigned long long)(~__float_as_uint(sc4[k])) << 32) | (uint32_t)i;
        }
        p++;
      }
    }
  }

  gbar(bar_cnt, bar_gen, tid);

  // ================= P2: compaction + rank + decode (blocks 0..127) =================
  if (bid < NTILE * BATCH) {
    const int b = bid >> 5;
    const int r = bid & 31;        // owns candidates [r*64, r*64+64)
    if (tid < 64) {
      uint32_t c = cnt_blk[b * 64 + tid];
      uint32_t cc = min(c, (uint32_t)CAP);
      scnt[tid] = cc;
      uint32_t x = cc;
      for (int off = 1; off < 64; off <<= 1) {
        uint32_t u = __shfl_up(x, off, 64);
        if (lane >= off) x += u;
      }
      sbs[tid] = x - cc;
      unsigned long long ov = __ballot(c > (uint32_t)CAP);
      if (tid == 63) { meta[0] = x; meta[1] = (ov != 0ULL) ? 1u : 0u; }
    }
    __syncthreads();
    uint32_t nsum = meta[0];
    int n = min((int)nsum, MMAX);
    uint32_t flag = meta[1] | ((nsum > (uint32_t)MMAX) ? 1u : 0u);
    if (r == 0 && tid == 0) {
      ctrs[b] = (uint32_t)n;
      ctrs[8 + b] = flag;
    }
    if (tid < 64) cnt2[(size_t)b * MMAX + r * 64 + tid] = 0u;  // 32 blocks x 64 = MMAX
    // compact: thread group of 4 per source block
    {
      int k = tid >> 2, q = tid & 3;
      uint32_t cb = sbs[k], cc = scnt[k];
      const unsigned long long* src = keys_raw + ((size_t)b * 64 + k) * CAP;
      for (uint32_t o = q; o < cc; o += 4) {
        uint32_t d = cb + o;
        if (d < (uint32_t)MMAX) sk[d] = src[o];
      }
    }
    for (int i = tid; i < MMAX; i += 256) if (i >= n) sk[i] = ~0ULL;
    __syncthreads();
    // rank my 64 candidates: each wave counts one 512-key window (broadcast reads)
    int c = r * 64 + lane;
    uint32_t partial = 0;
    if (c < n) {
      unsigned long long myk = sk[c];
      const ulonglong2* p2 = (const ulonglong2*)(sk + (size_t)wid * 512);
      for (int it = 0; it < 256; it += 4) {
        ulonglong2 a = p2[it], bq = p2[it + 1], cq = p2[it + 2], dq = p2[it + 3];
        partial += (uint32_t)(a.x < myk) + (uint32_t)(a.y < myk) +
                   (uint32_t)(bq.x < myk) + (uint32_t)(bq.y < myk) +
                   (uint32_t)(cq.x < myk) + (uint32_t)(cq.y < myk) +
                   (uint32_t)(dq.x < myk) + (uint32_t)(dq.y < myk);
      }
    }
    psum[wid * 64 + lane] = partial;
    __syncthreads();
    if (tid < 64) {
      int cc = r * 64 + tid;
      if (cc < n) {
        uint32_t rank = psum[tid] + psum[64 + tid] + psum[128 + tid] + psum[192 + tid];
        if (rank < (uint32_t)MMAX) {
          unsigned long long key = sk[cc];
          int i = (int)(uint32_t)key;
          float wmax = im_info[b * 3 + 1] - 1.0f;
          float hmax = im_info[b * 3 + 0] - 1.0f;
          float x1, y1, x2, y2;
          decode_box(anchors4, deltas4, b, i, wmax, hmax, x1, y1, x2, y2);
          sboxes[(size_t)b * MMAX + rank] = make_float4(x1, y1, x2, y2);
          slev[(size_t)b * MMAX + rank] = ids[i];
        }
      }
    }
  }

  gbar(bar_cnt, bar_gen, tid);

  // ================= P3: tiled all-pairs suppressor detection =================
  // 1024 wave-slots grid-stride the NPAIRS*BATCH tile tasks. i-tile held in
  // registers; broadcast via __shfl executed by ALL 64 lanes every iteration
  // (uniform trip count, guarded use) so every shfl is fully converged.
  {
    const int gwid = bid * 4 + wid;   // 0..1023
    for (int t = gwid; t < NPAIRS * BATCH; t += 1024) {
      const int b = t & 3;
      const int p = t >> 2;
      int tj = (int)((sqrtf(8.0f * (float)p + 1.0f) - 1.0f) * 0.5f);
      while ((tj + 1) * (tj + 2) / 2 <= p) ++tj;
      while (tj * (tj + 1) / 2 > p) --tj;
      int ti = p - tj * (tj + 1) / 2;
      int n = min((int)ctrs[b], MMAX);
      if (tj * 64 >= n) continue;   // uniform across wave

      int ii = ti * 64 + lane;
      float4 I = make_float4(0.f, 0.f, 0.f, 0.f);
      int ilv = -1;
      if (ii < n) {
        I = sboxes[(size_t)b * MMAX + ii];
        ilv = slev[(size_t)b * MMAX + ii];
      }
      int j = tj * 64 + lane;
      bool jv = (j < n);
      float4 J = make_float4(0.f, 0.f, 0.f, 0.f);
      int jl = -2;
      float aj = 0.0f;
      if (jv) {
        J = sboxes[(size_t)b * MMAX + j];
        jl = slev[(size_t)b * MMAX + j];
        aj = (J.z - J.x) * (J.w - J.y);
      }
      int imax = (ti == tj) ? lane : 64;  // diagonal: only i<j
      for (int k = 0; k < 64; ++k) {
        int   kl = __shfl(ilv, k, 64);
        float Ix = __shfl(I.x, k, 64);
        float Iy = __shfl(I.y, k, 64);
        float Iz = __shfl(I.z, k, 64);
        float Iw = __shfl(I.w, k, 64);
        if (!jv || k >= imax || kl != jl) continue;
        float xx1 = fmaxf(Ix, J.x), yy1 = fmaxf(Iy, J.y);
        float xx2 = fminf(Iz, J.z), yy2 = fminf(Iw, J.w);
        float inter = fmaxf(xx2 - xx1, 0.0f) * fmaxf(yy2 - yy1, 0.0f);
        float ai = (Iz - Ix) * (Iw - Iy);
        float iou = inter / fmaxf((ai + aj) - inter, 1e-6f);
        if (iou > NMS_T) {
          uint32_t s = atomicAdd(&cnt2[(size_t)b * MMAX + j], 1u);
          if (s < (uint32_t)KSUP) suplist[((size_t)b * MMAX + j) * KSUP + s] = ti * 64 + k;
          else atomicOr(&ctrs[8 + b], 1u);  // suppressor-list overflow -> fallback
        }
      }
    }
  }

  gbar(bar_cnt, bar_gen, tid);

  // ================= P4: exact ordered resolution + output (blocks 0..3) =================
  if (bid < BATCH) {
    const int b = bid;
    int n = min((int)ctrs[b], MMAX);
    const int jb = tid * 8;   // 256 threads x 8 = MMAX
    uint32_t cj[8];
    uint32_t uf = 0, usum = 0;
#pragma unroll
    for (int k = 0; k < 8; ++k) {
      int j = jb + k;
      uint32_t c = (j < n) ? cnt2[(size_t)b * MMAX + j] : 0u;
      cj[k] = c;
      kept[j] = (j < n && c == 0u) ? 1 : 0;
      uint32_t u = (j < n && c > 0u) ? 1u : 0u;
      uf |= (u << k); usum += u;
    }
    uint32_t tot_unc;
    uint32_t base = blockscan(usum, wsum, tid, &tot_unc);
    {
      uint32_t p = base;
#pragma unroll
      for (int k = 0; k < 8; ++k) {
        if ((uf >> k) & 1u) {
          if (p < (uint32_t)UNC) {
            int j = jb + k;
            int m = (int)min(cj[k], (uint32_t)KSUP);
            unc[p] = (uint16_t)j; supn[p] = (uint8_t)m;
            for (int s = 0; s < m; ++s)
              supld[p][s] = suplist[((size_t)b * MMAX + j) * KSUP + s];
          }
          p++;
        }
      }
    }
    __syncthreads();
    if (tid < 64) {  // wave 0: exact greedy resolution in ascending rank order
      int nu = (int)min(tot_unc, (uint32_t)UNC);
      for (int u = 0; u < nu; ++u) {
        int m = (int)supn[u];
        int pred = (tid < m) ? (int)kept[supld[u][tid]] : 0;
        unsigned long long bal = __ballot(pred);
        if (tid == 0) kept[unc[u]] = (bal == 0ULL) ? 1 : 0;
      }
    }
    __syncthreads();
    uint32_t kf = 0, ksum = 0;
#pragma unroll
    for (int k = 0; k < 8; ++k) {
      uint32_t kk = kept[jb + k];
      kf |= (kk << k); ksum += kk;
    }
    uint32_t total;
    uint32_t pb = blockscan(ksum, wsum, tid, &total);
    {
      uint32_t p = pb;
#pragma unroll
      for (int k = 0; k < 8; ++k) {
        if ((kf >> k) & 1u) {
          if (p < (uint32_t)TOPN) {
            float4 bx = sboxes[(size_t)b * MMAX + jb + k];
            size_t o = ((size_t)b * TOPN + p) * 5;
            out[o] = (float)b; out[o+1] = bx.x; out[o+2] = bx.y; out[o+3] = bx.z; out[o+4] = bx.w;
          }
          p++;
        }
      }
    }
    for (int t = tid; t < TOPN; t += 256) {
      if ((uint32_t)t >= total) {
        size_t o = ((size_t)b * TOPN + t) * 5;
        out[o] = (float)b; out[o+1] = 0.0f; out[o+2] = 0.0f; out[o+3] = 0.0f; out[o+4] = 0.0f;
      }
    }

    bool needFB = (ctrs[8 + b] != 0u) || (total < (uint32_t)TOPN) || (tot_unc > (uint32_t)UNC);
    if (needFB) {
      // ---------- exact brute-force fallback (block-uniform path, 256 threads) ----------
      const float wmax = im_info[b * 3 + 1] - 1.0f;
      const float hmax = im_info[b * 3 + 0] - 1.0f;
      __syncthreads();  // order resolve-phase writes before overwrite
      float mx = 0.0f;
      for (int i = tid; i < NB; i += 256) {
        float x1, y1, x2, y2;
        decode_box(anchors4, deltas4, b, i, wmax, hmax, x1, y1, x2, y2);
        mx = fmaxf(mx, fmaxf(fmaxf(x1, y1), fmaxf(x2, y2)));
      }
      for (int o = 32; o > 0; o >>= 1) mx = fmaxf(mx, __shfl_xor(mx, o, 64));
      if ((tid & 63) == 0) fm[tid >> 6] = mx;
      __syncthreads();
      if (tid == 0) fm[0] = fmaxf(fmaxf(fm[0], fm[1]), fmaxf(fm[2], fm[3]));
      for (int i = tid; i < NB / 32; i += 256) mask[i] = 0u;
      __syncthreads();
      float max_c = fm[0] + 1.0f;
      for (int it = 0; it < TOPN; ++it) {
        float bv = -3e38f; int bi = 0x7fffffff;
        for (int i = tid; i < NB; i += 256) {
          bool sup = (mask[i >> 5] >> (i & 31)) & 1u;
          float v = sup ? NEGV : scores[(size_t)b * NB + i];
          if (v > bv || (v == bv && i < bi)) { bv = v; bi = i; }
        }
        rv[tid] = bv; ri[tid] = bi;
        __syncthreads();
        for (int s = 128; s > 0; s >>= 1) {
          if (tid < s) {
            float v2 = rv[tid + s]; int i2 = ri[tid + s];
            if (v2 > rv[tid] || (v2 == rv[tid] && i2 < ri[tid])) { rv[tid] = v2; ri[tid] = i2; }
          }
          __syncthreads();
        }
        int ii = ri[0]; float vv = rv[0];
        bool valid = vv > NEGV * 0.5f;
        if (!valid) {
          if (tid == 0) {
            size_t o = ((size_t)b * TOPN + it) * 5;
            out[o] = (float)b; out[o+1] = 0; out[o+2] = 0; out[o+3] = 0; out[o+4] = 0;
          }
          __syncthreads();
          continue;
        }
        float x1, y1, x2, y2;
        decode_box(anchors4, deltas4, b, ii, wmax, hmax, x1, y1, x2, y2);
        int lv = ids[ii];
        float off = (float)lv * max_c;
        float s0 = x1 + off, s1 = y1 + off, s2 = x2 + off, s3 = y2 + off;
        float a1 = (s2 - s0) * (s3 - s1);
        if (tid == 0) {
          size_t o = ((size_t)b * TOPN + it) * 5;
          out[o] = (float)b; out[o+1] = x1; out[o+2] = y1; out[o+3] = x2; out[o+4] = y2;
        }
        for (int j = tid; j < NB; j += 256) {
          if ((mask[j >> 5] >> (j & 31)) & 1u) continue;
          if (ids[j] != lv) continue;  // cross-level IoU exactly 0 under offset geometry
          float bx1, by1, bx2, by2;
          decode_box(anchors4, deltas4, b, j, wmax, hmax, bx1, by1, bx2, by2);
          float t0 = bx1 + off, t1 = by1 + off, t2 = bx2 + off, t3 = by2 + off;
          float xx1 = fmaxf(s0, t0), yy1 = fmaxf(s1, t1);
          float xx2 = fminf(s2, t2), yy2 = fminf(s3, t3);
          float inter = fmaxf(xx2 - xx1, 0.0f) * fmaxf(yy2 - yy1, 0.0f);
          float a2r = (t2 - t0) * (t3 - t1);
          float iou = inter / fmaxf(a1 + a2r - inter, 1e-6f);
          if (iou > NMS_T) atomicOr(&mask[j >> 5], 1u << (j & 31));
        }
        if (tid == 0) atomicOr(&mask[ii >> 5], 1u << (ii & 31));
        __syncthreads();
      }
    }
  }
}

extern "C" void kernel_launch(void* const* d_in, const int* in_sizes, int n_in,
                              void* d_out, int out_size, void* d_ws, size_t ws_size,
                              hipStream_t stream) {
  const float*  scores   = (const float*)d_in[0];
  const float4* deltas4  = (const float4*)d_in[1];
  const float4* anchors4 = (const float4*)d_in[2];
  const float*  im_info  = (const float*)d_in[3];
  const int*    ids      = (const int*)d_in[4];
  float* out = (float*)d_out;

  char* ws = (char*)d_ws;
  uint32_t*           ctrs     = (uint32_t*)ws;
  uint32_t*           cnt_blk  = (uint32_t*)(ws + OFF_CBLK);
  unsigned long long* keys_raw = (unsigned long long*)(ws + OFF_KRAW);
  float4*             sboxes   = (float4*)(ws + OFF_SBOX);
  int*                slev     = (int*)(ws + OFF_SLEV);
  uint32_t*           cnt2     = (uint32_t*)(ws + OFF_CNT2);
  int*                suplist  = (int*)(ws + OFF_SUP);

  hipLaunchKernelGGL(k_init, dim3(1), dim3(64), 0, stream, ctrs);
  hipLaunchKernelGGL(k_fused, dim3(GRIDN), dim3(256), 0, stream,
                     scores, deltas4, anchors4, im_info, ids,
                     keys_raw, cnt_blk, ctrs, sboxes, slev, cnt2, suplist, out);
}

// Round 3
// 143.063 us; speedup vs baseline: 1.4402x; 1.4402x over previous
//
#include <hip/hip_runtime.h>
#include <stdint.h>

#define NB     65536
#define BATCH  4
#define TOPN   1000
#define MMAX   2048
#define NTILE  (MMAX / 64)                 // 32
#define NPAIRS (NTILE * (NTILE + 1) / 2)   // 528
#define CAP    128                         // per-prep-block candidate region
#define KSUP   8
#define UNC    128
#define THRESH 0.974f
#define NEGV   (-1e9f)
#define NMS_T  0.7f
#define GRIDN  256                         // fused-kernel grid size (1 block/CU)
#define NSLOT  16                          // barrier arrival slots (separate lines)
#define NMIRR  8                           // generation mirrors (separate lines)

// ws layout (bytes):
//   ctrs u32[16]: [0..3]=n, [8..11]=fallback flag
//   barrier area at OFF_BAR: 25 u32 words spread 64B apart:
//     word (s*16)        s=0..15  : slot arrival counters
//     word (16*16)                : root counter
//     word ((17+m)*16)   m=0..7   : generation mirrors
#define OFF_CBLK   64
#define OFF_KRAW   1088
#define OFF_SBOX   263232
#define OFF_SLEV   394304
#define OFF_CNT2   427072
#define OFF_SUP    459840
#define OFF_BAR    721984                  // 64B-aligned; area = 1600 B

__device__ __forceinline__ void decode_box(const float4* __restrict__ anchors4,
                                           const float4* __restrict__ deltas4,
                                           int b, int i, float wmax, float hmax,
                                           float& x1, float& y1, float& x2, float& y2) {
  float4 a = anchors4[i];
  float4 d = deltas4[(size_t)b * NB + i];
  float ws = a.z - a.x + 1.0f;
  float hs = a.w - a.y + 1.0f;
  float cx = a.x + 0.5f * ws;
  float cy = a.y + 0.5f * hs;
  float pcx = d.x * ws + cx;
  float pcy = d.y * hs + cy;
  float pw = expf(d.z) * ws;
  float ph = expf(d.w) * hs;
  x1 = pcx - 0.5f * pw; y1 = pcy - 0.5f * ph;
  x2 = pcx + 0.5f * pw; y2 = pcy + 0.5f * ph;
  x1 = fminf(fmaxf(x1, 0.0f), wmax);
  y1 = fminf(fmaxf(y1, 0.0f), hmax);
  x2 = fminf(fmaxf(x2, 0.0f), wmax);
  y2 = fminf(fmaxf(y2, 0.0f), hmax);
}

// block-wide exclusive scan, 256 threads (4 waves). wsum: u32[5].
__device__ __forceinline__ uint32_t blockscan(uint32_t v, volatile uint32_t* wsum,
                                              int tid, uint32_t* total) {
  __syncthreads();
  int lane = tid & 63, wid = tid >> 6;
  uint32_t x = v;
  for (int off = 1; off < 64; off <<= 1) {
    uint32_t u = __shfl_up(x, off, 64);
    if (lane >= off) x += u;
  }
  if (lane == 63) wsum[wid] = x;
  __syncthreads();
  if (tid == 0) {
    uint32_t run = 0;
    for (int w = 0; w < 4; ++w) { uint32_t t = wsum[w]; wsum[w] = run; run += t; }
    wsum[4] = run;
  }
  __syncthreads();
  *total = wsum[4];
  return x - v + wsum[wid];
}

// Decontended two-level grid barrier. Safe: grid(256) <= 256 CUs at 1 block/CU
// so all blocks co-resident. 16 slot counters + root + 8 gen mirrors, each on
// its own 64B line (no line sharing between RMW traffic and poll traffic).
// Polls are RELAXED with long sleeps; exactly one release fence at entry and
// one acquire fence at exit per block. Self-restoring (slots/root return to 0,
// mirrors monotonically increase).
__device__ __forceinline__ void gbar(uint32_t* bar, int bid, int tid) {
  __syncthreads();
  if (tid == 0) {
    uint32_t* slot = bar + (bid & (NSLOT - 1)) * 16;
    uint32_t* root = bar + NSLOT * 16;
    uint32_t* gmir = bar + (NSLOT + 1 + (bid & (NMIRR - 1))) * 16;
    uint32_t g = __hip_atomic_load(gmir, __ATOMIC_RELAXED, __HIP_MEMORY_SCOPE_AGENT);
    __threadfence();  // release: publish this block's phase writes device-wide
    uint32_t a = __hip_atomic_fetch_add(slot, 1u, __ATOMIC_RELAXED, __HIP_MEMORY_SCOPE_AGENT);
    if (a == (uint32_t)(GRIDN / NSLOT - 1)) {        // last arrival in this slot
      uint32_t r = __hip_atomic_fetch_add(root, 1u, __ATOMIC_RELAXED, __HIP_MEMORY_SCOPE_AGENT);
      if (r == (uint32_t)(NSLOT - 1)) {              // last slot overall
        __hip_atomic_store(root, 0u, __ATOMIC_RELAXED, __HIP_MEMORY_SCOPE_AGENT);
        for (int s = 0; s < NSLOT; ++s)
          __hip_atomic_store(bar + s * 16, 0u, __ATOMIC_RELAXED, __HIP_MEMORY_SCOPE_AGENT);
        for (int m = 0; m < NMIRR; ++m)              // resets ordered before release
          __hip_atomic_fetch_add(bar + (NSLOT + 1 + m) * 16, 1u,
                                 __ATOMIC_RELEASE, __HIP_MEMORY_SCOPE_AGENT);
      }
    }
    while (__hip_atomic_load(gmir, __ATOMIC_RELAXED, __HIP_MEMORY_SCOPE_AGENT) == g)
      __builtin_amdgcn_s_sleep(32);
    __threadfence();  // acquire: invalidate stale cached lines before next phase
  }
  __syncthreads();
}

__global__ void k_init(uint32_t* bar) {
  // words 0..24 spread 64B apart: slots(0..15), root(16), mirrors(17..24)
  if (threadIdx.x < NSLOT + 1 + NMIRR)
    __hip_atomic_store(&bar[threadIdx.x * 16], 0u, __ATOMIC_RELAXED,
                       __HIP_MEMORY_SCOPE_AGENT);
}

// Fused pipeline: prep -> rank -> pairs -> out, separated by grid barriers.
// 256 blocks x 256 threads = 1 block/CU.
__global__ __launch_bounds__(256) void k_fused(
    const float* __restrict__ scores, const float4* __restrict__ deltas4,
    const float4* __restrict__ anchors4, const float* __restrict__ im_info,
    const int* __restrict__ ids,
    unsigned long long* __restrict__ keys_raw, uint32_t* __restrict__ cnt_blk,
    uint32_t* ctrs, float4* __restrict__ sboxes, int* __restrict__ slev,
    uint32_t* __restrict__ cnt2, int* __restrict__ suplist,
    uint32_t* __restrict__ bar, float* __restrict__ out) {
  const int bid = blockIdx.x;
  const int tid = threadIdx.x;
  const int lane = tid & 63, wid = tid >> 6;

  // ---- shared memory (static; lifetimes separated by grid barriers) ----
  __shared__ uint32_t wsum[17];                 // P1 + P4 scans (uses [0..4])
  __shared__ unsigned long long sk[MMAX];       // P2: 16 KB
  __shared__ uint32_t scnt[64], sbs[64];        // P2
  __shared__ uint32_t psum[256];                // P2
  __shared__ uint32_t meta[2];                  // P2
  __shared__ uint8_t  kept[MMAX];               // P4
  __shared__ uint16_t unc[UNC];                 // P4
  __shared__ int      supld[UNC][KSUP];         // P4: 4 KB
  __shared__ uint8_t  supn[UNC];                // P4
  __shared__ uint32_t mask[NB / 32];            // P4 fallback: 8 KB
  __shared__ float    rv[256];                  // P4 fallback
  __shared__ int      ri[256];                  // P4 fallback
  __shared__ float    fm[4];                    // P4 fallback

  // ================= P1: score-threshold scan (all 256 blocks) =================
  {
    const int b = bid >> 6;        // 64 blocks / image
    const int blk = bid & 63;      // 1024 scores / block
    const float4* s4 = (const float4*)scores + (size_t)b * (NB / 4) + (size_t)blk * 256 + tid;
    float4 s = *s4;
    float sc4[4] = {s.x, s.y, s.z, s.w};
    uint32_t cmask = 0, ccount = 0;
#pragma unroll
    for (int k = 0; k < 4; ++k)
      if (sc4[k] >= THRESH) { cmask |= (1u << k); ccount++; }
    uint32_t total;
    uint32_t p = blockscan(ccount, wsum, tid, &total);
    if (tid == 0) cnt_blk[bid] = total;  // TRUE count (P2 detects >CAP)
    unsigned long long* dst = keys_raw + (size_t)bid * CAP;
#pragma unroll
    for (int k = 0; k < 4; ++k) {
      if (cmask & (1u << k)) {
        if (p < (uint32_t)CAP) {
          int i = (blk << 10) + (tid << 2) + k;
          dst[p] = ((unsigned long long)(~__float_as_uint(sc4[k])) << 32) | (uint32_t)i;
        }
        p++;
      }
    }
  }

  gbar(bar, bid, tid);

  // ================= P2: compaction + rank + decode (blocks 0..127) =================
  if (bid < NTILE * BATCH) {
    const int b = bid >> 5;
    const int r = bid & 31;        // owns candidates [r*64, r*64+64)
    if (tid < 64) {
      uint32_t c = cnt_blk[b * 64 + tid];
      uint32_t cc = min(c, (uint32_t)CAP);
      scnt[tid] = cc;
      uint32_t x = cc;
      for (int off = 1; off < 64; off <<= 1) {
        uint32_t u = __shfl_up(x, off, 64);
        if (lane >= off) x += u;
      }
      sbs[tid] = x - cc;
      unsigned long long ov = __ballot(c > (uint32_t)CAP);
      if (tid == 63) { meta[0] = x; meta[1] = (ov != 0ULL) ? 1u : 0u; }
    }
    __syncthreads();
    uint32_t nsum = meta[0];
    int n = min((int)nsum, MMAX);
    uint32_t flag = meta[1] | ((nsum > (uint32_t)MMAX) ? 1u : 0u);
    if (r == 0 && tid == 0) {
      ctrs[b] = (uint32_t)n;
      ctrs[8 + b] = flag;
    }
    if (tid < 64) cnt2[(size_t)b * MMAX + r * 64 + tid] = 0u;  // 32 blocks x 64 = MMAX
    // compact: thread group of 4 per source block
    {
      int k = tid >> 2, q = tid & 3;
      uint32_t cb = sbs[k], cc = scnt[k];
      const unsigned long long* src = keys_raw + ((size_t)b * 64 + k) * CAP;
      for (uint32_t o = q; o < cc; o += 4) {
        uint32_t d = cb + o;
        if (d < (uint32_t)MMAX) sk[d] = src[o];
      }
    }
    for (int i = tid; i < MMAX; i += 256) if (i >= n) sk[i] = ~0ULL;
    __syncthreads();
    // rank my 64 candidates: each wave counts one 512-key window (broadcast reads)
    int c = r * 64 + lane;
    uint32_t partial = 0;
    if (c < n) {
      unsigned long long myk = sk[c];
      const ulonglong2* p2 = (const ulonglong2*)(sk + (size_t)wid * 512);
      for (int it = 0; it < 256; it += 4) {
        ulonglong2 a = p2[it], bq = p2[it + 1], cq = p2[it + 2], dq = p2[it + 3];
        partial += (uint32_t)(a.x < myk) + (uint32_t)(a.y < myk) +
                   (uint32_t)(bq.x < myk) + (uint32_t)(bq.y < myk) +
                   (uint32_t)(cq.x < myk) + (uint32_t)(cq.y < myk) +
                   (uint32_t)(dq.x < myk) + (uint32_t)(dq.y < myk);
      }
    }
    psum[wid * 64 + lane] = partial;
    __syncthreads();
    if (tid < 64) {
      int cc = r * 64 + tid;
      if (cc < n) {
        uint32_t rank = psum[tid] + psum[64 + tid] + psum[128 + tid] + psum[192 + tid];
        if (rank < (uint32_t)MMAX) {
          unsigned long long key = sk[cc];
          int i = (int)(uint32_t)key;
          float wmax = im_info[b * 3 + 1] - 1.0f;
          float hmax = im_info[b * 3 + 0] - 1.0f;
          float x1, y1, x2, y2;
          decode_box(anchors4, deltas4, b, i, wmax, hmax, x1, y1, x2, y2);
          sboxes[(size_t)b * MMAX + rank] = make_float4(x1, y1, x2, y2);
          slev[(size_t)b * MMAX + rank] = ids[i];
        }
      }
    }
  }

  gbar(bar, bid, tid);

  // ================= P3: tiled all-pairs suppressor detection =================
  // 1024 wave-slots grid-stride the NPAIRS*BATCH tile tasks. i-tile held in
  // registers; broadcast via __shfl executed by ALL 64 lanes every iteration
  // (uniform trip count, guarded use) so every shfl is fully converged.
  {
    const int gwid = bid * 4 + wid;   // 0..1023
    for (int t = gwid; t < NPAIRS * BATCH; t += 1024) {
      const int b = t & 3;
      const int p = t >> 2;
      int tj = (int)((sqrtf(8.0f * (float)p + 1.0f) - 1.0f) * 0.5f);
      while ((tj + 1) * (tj + 2) / 2 <= p) ++tj;
      while (tj * (tj + 1) / 2 > p) --tj;
      int ti = p - tj * (tj + 1) / 2;
      int n = min((int)ctrs[b], MMAX);
      if (tj * 64 >= n) continue;   // uniform across wave

      int ii = ti * 64 + lane;
      float4 I = make_float4(0.f, 0.f, 0.f, 0.f);
      int ilv = -1;
      if (ii < n) {
        I = sboxes[(size_t)b * MMAX + ii];
        ilv = slev[(size_t)b * MMAX + ii];
      }
      int j = tj * 64 + lane;
      bool jv = (j < n);
      float4 J = make_float4(0.f, 0.f, 0.f, 0.f);
      int jl = -2;
      float aj = 0.0f;
      if (jv) {
        J = sboxes[(size_t)b * MMAX + j];
        jl = slev[(size_t)b * MMAX + j];
        aj = (J.z - J.x) * (J.w - J.y);
      }
      int imax = (ti == tj) ? lane : 64;  // diagonal: only i<j
      for (int k = 0; k < 64; ++k) {
        int   kl = __shfl(ilv, k, 64);
        float Ix = __shfl(I.x, k, 64);
        float Iy = __shfl(I.y, k, 64);
        float Iz = __shfl(I.z, k, 64);
        float Iw = __shfl(I.w, k, 64);
        if (!jv || k >= imax || kl != jl) continue;
        float xx1 = fmaxf(Ix, J.x), yy1 = fmaxf(Iy, J.y);
        float xx2 = fminf(Iz, J.z), yy2 = fminf(Iw, J.w);
        float inter = fmaxf(xx2 - xx1, 0.0f) * fmaxf(yy2 - yy1, 0.0f);
        float ai = (Iz - Ix) * (Iw - Iy);
        float iou = inter / fmaxf((ai + aj) - inter, 1e-6f);
        if (iou > NMS_T) {
          uint32_t s = atomicAdd(&cnt2[(size_t)b * MMAX + j], 1u);
          if (s < (uint32_t)KSUP) suplist[((size_t)b * MMAX + j) * KSUP + s] = ti * 64 + k;
          else atomicOr(&ctrs[8 + b], 1u);  // suppressor-list overflow -> fallback
        }
      }
    }
  }

  gbar(bar, bid, tid);

  // ================= P4: exact ordered resolution + output (blocks 0..3) =================
  if (bid < BATCH) {
    const int b = bid;
    int n = min((int)ctrs[b], MMAX);
    const int jb = tid * 8;   // 256 threads x 8 = MMAX
    uint32_t cj[8];
    uint32_t uf = 0, usum = 0;
#pragma unroll
    for (int k = 0; k < 8; ++k) {
      int j = jb + k;
      uint32_t c = (j < n) ? cnt2[(size_t)b * MMAX + j] : 0u;
      cj[k] = c;
      kept[j] = (j < n && c == 0u) ? 1 : 0;
      uint32_t u = (j < n && c > 0u) ? 1u : 0u;
      uf |= (u << k); usum += u;
    }
    uint32_t tot_unc;
    uint32_t base = blockscan(usum, wsum, tid, &tot_unc);
    {
      uint32_t p = base;
#pragma unroll
      for (int k = 0; k < 8; ++k) {
        if ((uf >> k) & 1u) {
          if (p < (uint32_t)UNC) {
            int j = jb + k;
            int m = (int)min(cj[k], (uint32_t)KSUP);
            unc[p] = (uint16_t)j; supn[p] = (uint8_t)m;
            for (int s = 0; s < m; ++s)
              supld[p][s] = suplist[((size_t)b * MMAX + j) * KSUP + s];
          }
          p++;
        }
      }
    }
    __syncthreads();
    if (tid < 64) {  // wave 0: exact greedy resolution in ascending rank order
      int nu = (int)min(tot_unc, (uint32_t)UNC);
      for (int u = 0; u < nu; ++u) {
        int m = (int)supn[u];
        int pred = (tid < m) ? (int)kept[supld[u][tid]] : 0;
        unsigned long long bal = __ballot(pred);
        if (tid == 0) kept[unc[u]] = (bal == 0ULL) ? 1 : 0;
      }
    }
    __syncthreads();
    uint32_t kf = 0, ksum = 0;
#pragma unroll
    for (int k = 0; k < 8; ++k) {
      uint32_t kk = kept[jb + k];
      kf |= (kk << k); ksum += kk;
    }
    uint32_t total;
    uint32_t pb = blockscan(ksum, wsum, tid, &total);
    {
      uint32_t p = pb;
#pragma unroll
      for (int k = 0; k < 8; ++k) {
        if ((kf >> k) & 1u) {
          if (p < (uint32_t)TOPN) {
            float4 bx = sboxes[(size_t)b * MMAX + jb + k];
            size_t o = ((size_t)b * TOPN + p) * 5;
            out[o] = (float)b; out[o+1] = bx.x; out[o+2] = bx.y; out[o+3] = bx.z; out[o+4] = bx.w;
          }
          p++;
        }
      }
    }
    for (int t = tid; t < TOPN; t += 256) {
      if ((uint32_t)t >= total) {
        size_t o = ((size_t)b * TOPN + t) * 5;
        out[o] = (float)b; out[o+1] = 0.0f; out[o+2] = 0.0f; out[o+3] = 0.0f; out[o+4] = 0.0f;
      }
    }

    bool needFB = (ctrs[8 + b] != 0u) || (total < (uint32_t)TOPN) || (tot_unc > (uint32_t)UNC);
    if (needFB) {
      // ---------- exact brute-force fallback (block-uniform path, 256 threads) ----------
      const float wmax = im_info[b * 3 + 1] - 1.0f;
      const float hmax = im_info[b * 3 + 0] - 1.0f;
      __syncthreads();  // order resolve-phase writes before overwrite
      float mx = 0.0f;
      for (int i = tid; i < NB; i += 256) {
        float x1, y1, x2, y2;
        decode_box(anchors4, deltas4, b, i, wmax, hmax, x1, y1, x2, y2);
        mx = fmaxf(mx, fmaxf(fmaxf(x1, y1), fmaxf(x2, y2)));
      }
      for (int o = 32; o > 0; o >>= 1) mx = fmaxf(mx, __shfl_xor(mx, o, 64));
      if ((tid & 63) == 0) fm[tid >> 6] = mx;
      __syncthreads();
      if (tid == 0) fm[0] = fmaxf(fmaxf(fm[0], fm[1]), fmaxf(fm[2], fm[3]));
      for (int i = tid; i < NB / 32; i += 256) mask[i] = 0u;
      __syncthreads();
      float max_c = fm[0] + 1.0f;
      for (int it = 0; it < TOPN; ++it) {
        float bv = -3e38f; int bi = 0x7fffffff;
        for (int i = tid; i < NB; i += 256) {
          bool sup = (mask[i >> 5] >> (i & 31)) & 1u;
          float v = sup ? NEGV : scores[(size_t)b * NB + i];
          if (v > bv || (v == bv && i < bi)) { bv = v; bi = i; }
        }
        rv[tid] = bv; ri[tid] = bi;
        __syncthreads();
        for (int s = 128; s > 0; s >>= 1) {
          if (tid < s) {
            float v2 = rv[tid + s]; int i2 = ri[tid + s];
            if (v2 > rv[tid] || (v2 == rv[tid] && i2 < ri[tid])) { rv[tid] = v2; ri[tid] = i2; }
          }
          __syncthreads();
        }
        int ii = ri[0]; float vv = rv[0];
        bool valid = vv > NEGV * 0.5f;
        if (!valid) {
          if (tid == 0) {
            size_t o = ((size_t)b * TOPN + it) * 5;
            out[o] = (float)b; out[o+1] = 0; out[o+2] = 0; out[o+3] = 0; out[o+4] = 0;
          }
          __syncthreads();
          continue;
        }
        float x1, y1, x2, y2;
        decode_box(anchors4, deltas4, b, ii, wmax, hmax, x1, y1, x2, y2);
        int lv = ids[ii];
        float off = (float)lv * max_c;
        float s0 = x1 + off, s1 = y1 + off, s2 = x2 + off, s3 = y2 + off;
        float a1 = (s2 - s0) * (s3 - s1);
        if (tid == 0) {
          size_t o = ((size_t)b * TOPN + it) * 5;
          out[o] = (float)b; out[o+1] = x1; out[o+2] = y1; out[o+3] = x2; out[o+4] = y2;
        }
        for (int j = tid; j < NB; j += 256) {
          if ((mask[j >> 5] >> (j & 31)) & 1u) continue;
          if (ids[j] != lv) continue;  // cross-level IoU exactly 0 under offset geometry
          float bx1, by1, bx2, by2;
          decode_box(anchors4, deltas4, b, j, wmax, hmax, bx1, by1, bx2, by2);
          float t0 = bx1 + off, t1 = by1 + off, t2 = bx2 + off, t3 = by2 + off;
          float xx1 = fmaxf(s0, t0), yy1 = fmaxf(s1, t1);
          float xx2 = fminf(s2, t2), yy2 = fminf(s3, t3);
          float inter = fmaxf(xx2 - xx1, 0.0f) * fmaxf(yy2 - yy1, 0.0f);
          float a2r = (t2 - t0) * (t3 - t1);
          float iou = inter / fmaxf(a1 + a2r - inter, 1e-6f);
          if (iou > NMS_T) atomicOr(&mask[j >> 5], 1u << (j & 31));
        }
        if (tid == 0) atomicOr(&mask[ii >> 5], 1u << (ii & 31));
        __syncthreads();
      }
    }
  }
}

extern "C" void kernel_launch(void* const* d_in, const int* in_sizes, int n_in,
                              void* d_out, int out_size, void* d_ws, size_t ws_size,
                              hipStream_t stream) {
  const float*  scores   = (const float*)d_in[0];
  const float4* deltas4  = (const float4*)d_in[1];
  const float4* anchors4 = (const float4*)d_in[2];
  const float*  im_info  = (const float*)d_in[3];
  const int*    ids      = (const int*)d_in[4];
  float* out = (float*)d_out;

  char* ws = (char*)d_ws;
  uint32_t*           ctrs     = (uint32_t*)ws;
  uint32_t*           cnt_blk  = (uint32_t*)(ws + OFF_CBLK);
  unsigned long long* keys_raw = (unsigned long long*)(ws + OFF_KRAW);
  float4*             sboxes   = (float4*)(ws + OFF_SBOX);
  int*                slev     = (int*)(ws + OFF_SLEV);
  uint32_t*           cnt2     = (uint32_t*)(ws + OFF_CNT2);
  int*                suplist  = (int*)(ws + OFF_SUP);
  uint32_t*           bar      = (uint32_t*)(ws + OFF_BAR);

  hipLaunchKernelGGL(k_init, dim3(1), dim3(64), 0, stream, bar);
  hipLaunchKernelGGL(k_fused, dim3(GRIDN), dim3(256), 0, stream,
                     scores, deltas4, anchors4, im_info, ids,
                     keys_raw, cnt_blk, ctrs, sboxes, slev, cnt2, suplist, bar, out);
}

// Round 4
// 125.914 us; speedup vs baseline: 1.6363x; 1.1362x over previous
//
#include <hip/hip_runtime.h>
#include <stdint.h>

#define NB     65536
#define BATCH  4
#define TOPN   1000
#define MMAX   2048
#define NTILE  (MMAX / 64)                 // 32
#define NPAIRS (NTILE * (NTILE + 1) / 2)   // 528
#define CAP    128                         // per-prep-block candidate region
#define KSUP   8
#define UNC    128
#define THRESH 0.974f
#define NEGV   (-1e9f)
#define NMS_T  0.7f
#define GRIDN  256                         // fused-kernel grid size

// ws layout (bytes):
//   ctrs u32[16]: [0..3]=n, [8..11]=fallback flag
//   barrier area at OFF_BAR: 59 u32 words spread 64B apart (word = line*16):
//     L0..15  arrival slots        L16     arrival root
//     L17..24 gmirA mirrors        L25..32 flush_gen (per XCD, CAS)
//     L33     flush-done count     L34..41 gmirB mirrors
//     L42..49 inv_gen (per XCD)    L50..57 inv-done (per XCD)
//     L58     xmask (participating XCD bitmask)
#define OFF_CBLK   64
#define OFF_KRAW   1088
#define OFF_SBOX   263232
#define OFF_SLEV   394304
#define OFF_CNT2   427072
#define OFF_SUP    459840
#define OFF_BAR    721984                  // 64B-aligned; area = 3776 B

__device__ __forceinline__ void decode_box(const float4* __restrict__ anchors4,
                                           const float4* __restrict__ deltas4,
                                           int b, int i, float wmax, float hmax,
                                           float& x1, float& y1, float& x2, float& y2) {
  float4 a = anchors4[i];
  float4 d = deltas4[(size_t)b * NB + i];
  float ws = a.z - a.x + 1.0f;
  float hs = a.w - a.y + 1.0f;
  float cx = a.x + 0.5f * ws;
  float cy = a.y + 0.5f * hs;
  float pcx = d.x * ws + cx;
  float pcy = d.y * hs + cy;
  float pw = expf(d.z) * ws;
  float ph = expf(d.w) * hs;
  x1 = pcx - 0.5f * pw; y1 = pcy - 0.5f * ph;
  x2 = pcx + 0.5f * pw; y2 = pcy + 0.5f * ph;
  x1 = fminf(fmaxf(x1, 0.0f), wmax);
  y1 = fminf(fmaxf(y1, 0.0f), hmax);
  x2 = fminf(fmaxf(x2, 0.0f), wmax);
  y2 = fminf(fmaxf(y2, 0.0f), hmax);
}

// block-wide exclusive scan, 256 threads (4 waves). wsum: u32[5].
__device__ __forceinline__ uint32_t blockscan(uint32_t v, volatile uint32_t* wsum,
                                              int tid, uint32_t* total) {
  __syncthreads();
  int lane = tid & 63, wid = tid >> 6;
  uint32_t x = v;
  for (int off = 1; off < 64; off <<= 1) {
    uint32_t u = __shfl_up(x, off, 64);
    if (lane >= off) x += u;
  }
  if (lane == 63) wsum[wid] = x;
  __syncthreads();
  if (tid == 0) {
    uint32_t run = 0;
    for (int w = 0; w < 4; ++w) { uint32_t t = wsum[w]; wsum[w] = run; run += t; }
    wsum[4] = run;
  }
  __syncthreads();
  *total = wsum[4];
  return x - v + wsum[wid];
}

// Minimal-fence 3-stage grid barrier. All co-resident (256 blocks, >=1/CU fit).
// Stage A: decontended arrival (all RELAXED atomics, coherence-point ops).
// Stage B: after FULL arrival, one CAS-elected block per participating XCD does
//   buffer_wbl2 (whole-XCD-L2 writeback). Release when all XCDs flushed.
// Stage C: one elected block per XCD does buffer_inv sc0 sc1 (L1+L2); every
//   other block does an L1-only buffer_inv sc0 after its XCD's inv completes.
// Correctness: each block's stores are in its XCD L2 at arrival (compiler
// emits s_waitcnt vmcnt(0) before s_barrier); flush happens only after all
// arrivals; inv only after all flushes; inv drops only clean lines.
__device__ __forceinline__ void gbar(uint32_t* bar, int bid, int tid,
                                     uint32_t g, uint32_t xcc) {
  __syncthreads();
  if (tid == 0) {
    const uint32_t tgt = g + 1u;
    // ---- stage A: arrival ----
    uint32_t* slot = bar + (bid & 15) * 16;
    uint32_t* root = bar + 16 * 16;
    uint32_t* mA   = bar + (17 + (bid & 7)) * 16;
    uint32_t a = __hip_atomic_fetch_add(slot, 1u, __ATOMIC_RELAXED, __HIP_MEMORY_SCOPE_AGENT);
    if (a == 15u) {
      uint32_t r = __hip_atomic_fetch_add(root, 1u, __ATOMIC_RELAXED, __HIP_MEMORY_SCOPE_AGENT);
      if (r == 15u) {
        __hip_atomic_store(root, 0u, __ATOMIC_RELAXED, __HIP_MEMORY_SCOPE_AGENT);
        for (int s = 0; s < 16; ++s)
          __hip_atomic_store(bar + s * 16, 0u, __ATOMIC_RELAXED, __HIP_MEMORY_SCOPE_AGENT);
        asm volatile("s_waitcnt vmcnt(0)" ::: "memory");  // resets performed before release
        for (int m = 0; m < 8; ++m)
          __hip_atomic_fetch_add(bar + (17 + m) * 16, 1u, __ATOMIC_RELAXED,
                                 __HIP_MEMORY_SCOPE_AGENT);
      }
    }
    while (__hip_atomic_load(mA, __ATOMIC_RELAXED, __HIP_MEMORY_SCOPE_AGENT) < tgt)
      __builtin_amdgcn_s_sleep(8);
    // ---- stage B: one L2 writeback per participating XCD ----
    uint32_t* fg = bar + (25 + (int)xcc) * 16;
    uint32_t* fr = bar + 33 * 16;
    uint32_t* mB = bar + (34 + (bid & 7)) * 16;
    uint32_t expg = g;
    if (__hip_atomic_compare_exchange_strong(fg, &expg, tgt, __ATOMIC_RELAXED,
                                             __ATOMIC_RELAXED, __HIP_MEMORY_SCOPE_AGENT)) {
      asm volatile("buffer_wbl2 sc0 sc1\n\ts_waitcnt vmcnt(0)" ::: "memory");
      uint32_t nx = (uint32_t)__popc(__hip_atomic_load(bar + 58 * 16, __ATOMIC_RELAXED,
                                                       __HIP_MEMORY_SCOPE_AGENT));
      uint32_t f = __hip_atomic_fetch_add(fr, 1u, __ATOMIC_RELAXED, __HIP_MEMORY_SCOPE_AGENT);
      if (f == nx - 1u) {
        __hip_atomic_store(fr, 0u, __ATOMIC_RELAXED, __HIP_MEMORY_SCOPE_AGENT);
        asm volatile("s_waitcnt vmcnt(0)" ::: "memory");
        for (int m = 0; m < 8; ++m)
          __hip_atomic_fetch_add(bar + (34 + m) * 16, 1u, __ATOMIC_RELAXED,
                                 __HIP_MEMORY_SCOPE_AGENT);
      }
    }
    while (__hip_atomic_load(mB, __ATOMIC_RELAXED, __HIP_MEMORY_SCOPE_AGENT) < tgt)
      __builtin_amdgcn_s_sleep(4);
    // ---- stage C: one L2 invalidate per XCD + per-block L1 invalidate ----
    uint32_t* ig = bar + (42 + (int)xcc) * 16;
    uint32_t* id = bar + (50 + (int)xcc) * 16;
    expg = g;
    if (__hip_atomic_compare_exchange_strong(ig, &expg, tgt, __ATOMIC_RELAXED,
                                             __ATOMIC_RELAXED, __HIP_MEMORY_SCOPE_AGENT)) {
      asm volatile("buffer_inv sc0 sc1\n\ts_waitcnt vmcnt(0)" ::: "memory");
      __hip_atomic_store(id, tgt, __ATOMIC_RELAXED, __HIP_MEMORY_SCOPE_AGENT);
    } else {
      while (__hip_atomic_load(id, __ATOMIC_RELAXED, __HIP_MEMORY_SCOPE_AGENT) < tgt)
        __builtin_amdgcn_s_sleep(1);
      asm volatile("buffer_inv sc0\n\ts_waitcnt vmcnt(0)" ::: "memory");
    }
  }
  __syncthreads();
}

__global__ void k_init(uint32_t* bar) {
  if (threadIdx.x < 59)
    __hip_atomic_store(&bar[threadIdx.x * 16], 0u, __ATOMIC_RELAXED,
                       __HIP_MEMORY_SCOPE_AGENT);
}

// Fused pipeline: prep -> rank -> pairs -> out, separated by grid barriers.
__global__ __launch_bounds__(256) void k_fused(
    const float* __restrict__ scores, const float4* __restrict__ deltas4,
    const float4* __restrict__ anchors4, const float* __restrict__ im_info,
    const int* __restrict__ ids,
    unsigned long long* __restrict__ keys_raw, uint32_t* __restrict__ cnt_blk,
    uint32_t* ctrs, float4* __restrict__ sboxes, int* __restrict__ slev,
    uint32_t* __restrict__ cnt2, int* __restrict__ suplist,
    uint32_t* __restrict__ bar, float* __restrict__ out) {
  const int bid = blockIdx.x;
  const int tid = threadIdx.x;
  const int lane = tid & 63, wid = tid >> 6;

  uint32_t xcc = 0;
  asm volatile("s_getreg_b32 %0, hwreg(HW_REG_XCC_ID)" : "=s"(xcc));
  if (tid == 0)   // register this block's XCD; drained by first __syncthreads
    __hip_atomic_fetch_or(bar + 58 * 16, 1u << xcc, __ATOMIC_RELAXED,
                          __HIP_MEMORY_SCOPE_AGENT);

  // ---- shared memory (static; lifetimes separated by grid barriers) ----
  __shared__ uint32_t wsum[17];                 // P1 + P4 scans (uses [0..4])
  __shared__ unsigned long long sk[MMAX];       // P2: 16 KB
  __shared__ uint32_t scnt[64], sbs[64];        // P2
  __shared__ uint32_t psum[256];                // P2
  __shared__ uint32_t meta[2];                  // P2
  __shared__ uint8_t  kept[MMAX];               // P4: 0=unres 1=kept 2=supp
  __shared__ uint16_t unc[UNC];                 // P4
  __shared__ int      supld[UNC][KSUP];         // P4: 4 KB
  __shared__ uint8_t  supn[UNC];                // P4
  __shared__ uint16_t unr[UNC];                 // P4: unresolved-after-sweeps
  __shared__ uint32_t mask[NB / 32];            // P4 fallback: 8 KB
  __shared__ float    rv[256];                  // P4 fallback
  __shared__ int      ri[256];                  // P4 fallback
  __shared__ float    fm[4];                    // P4 fallback

  // ================= P1: score-threshold scan (all 256 blocks) =================
  {
    const int b = bid >> 6;        // 64 blocks / image
    const int blk = bid & 63;      // 1024 scores / block
    const float4* s4 = (const float4*)scores + (size_t)b * (NB / 4) + (size_t)blk * 256 + tid;
    float4 s = *s4;
    float sc4[4] = {s.x, s.y, s.z, s.w};
    uint32_t cmask = 0, ccount = 0;
#pragma unroll
    for (int k = 0; k < 4; ++k)
      if (sc4[k] >= THRESH) { cmask |= (1u << k); ccount++; }
    uint32_t total;
    uint32_t p = blockscan(ccount, wsum, tid, &total);
    if (tid == 0) cnt_blk[bid] = total;  // TRUE count (P2 detects >CAP)
    unsigned long long* dst = keys_raw + (size_t)bid * CAP;
#pragma unroll
    for (int k = 0; k < 4; ++k) {
      if (cmask & (1u << k)) {
        if (p < (uint32_t)CAP) {
          int i = (blk << 10) + (tid << 2) + k;
          dst[p] = ((unsigned long long)(~__float_as_uint(sc4[k])) << 32) | (uint32_t)i;
        }
        p++;
      }
    }
  }

  gbar(bar, bid, tid, 0u, xcc);

  // ================= P2: compaction + rank + decode (blocks 0..127) =================
  if (bid < NTILE * BATCH) {
    const int b = bid >> 5;
    const int r = bid & 31;        // owns candidates [r*64, r*64+64)
    if (tid < 64) {
      uint32_t c = cnt_blk[b * 64 + tid];
      uint32_t cc = min(c, (uint32_t)CAP);
      scnt[tid] = cc;
      uint32_t x = cc;
      for (int off = 1; off < 64; off <<= 1) {
        uint32_t u = __shfl_up(x, off, 64);
        if (lane >= off) x += u;
      }
      sbs[tid] = x - cc;
      unsigned long long ov = __ballot(c > (uint32_t)CAP);
      if (tid == 63) { meta[0] = x; meta[1] = (ov != 0ULL) ? 1u : 0u; }
    }
    __syncthreads();
    uint32_t nsum = meta[0];
    int n = min((int)nsum, MMAX);
    uint32_t flag = meta[1] | ((nsum > (uint32_t)MMAX) ? 1u : 0u);
    if (r == 0 && tid == 0) {
      ctrs[b] = (uint32_t)n;
      ctrs[8 + b] = flag;
    }
    if (tid < 64) cnt2[(size_t)b * MMAX + r * 64 + tid] = 0u;  // 32 blocks x 64 = MMAX
    // compact: thread group of 4 per source block
    {
      int k = tid >> 2, q = tid & 3;
      uint32_t cb = sbs[k], cc = scnt[k];
      const unsigned long long* src = keys_raw + ((size_t)b * 64 + k) * CAP;
      for (uint32_t o = q; o < cc; o += 4) {
        uint32_t d = cb + o;
        if (d < (uint32_t)MMAX) sk[d] = src[o];
      }
    }
    for (int i = tid; i < MMAX; i += 256) if (i >= n) sk[i] = ~0ULL;
    __syncthreads();
    // rank my 64 candidates: each wave counts one 512-key window (broadcast reads)
    int c = r * 64 + lane;
    uint32_t partial = 0;
    if (c < n) {
      unsigned long long myk = sk[c];
      const ulonglong2* p2 = (const ulonglong2*)(sk + (size_t)wid * 512);
      for (int it = 0; it < 256; it += 4) {
        ulonglong2 a = p2[it], bq = p2[it + 1], cq = p2[it + 2], dq = p2[it + 3];
        partial += (uint32_t)(a.x < myk) + (uint32_t)(a.y < myk) +
                   (uint32_t)(bq.x < myk) + (uint32_t)(bq.y < myk) +
                   (uint32_t)(cq.x < myk) + (uint32_t)(cq.y < myk) +
                   (uint32_t)(dq.x < myk) + (uint32_t)(dq.y < myk);
      }
    }
    psum[wid * 64 + lane] = partial;
    __syncthreads();
    if (tid < 64) {
      int cc = r * 64 + tid;
      if (cc < n) {
        uint32_t rank = psum[tid] + psum[64 + tid] + psum[128 + tid] + psum[192 + tid];
        if (rank < (uint32_t)MMAX) {
          unsigned long long key = sk[cc];
          int i = (int)(uint32_t)key;
          float wmax = im_info[b * 3 + 1] - 1.0f;
          float hmax = im_info[b * 3 + 0] - 1.0f;
          float x1, y1, x2, y2;
          decode_box(anchors4, deltas4, b, i, wmax, hmax, x1, y1, x2, y2);
          sboxes[(size_t)b * MMAX + rank] = make_float4(x1, y1, x2, y2);
          slev[(size_t)b * MMAX + rank] = ids[i];
        }
      }
    }
  }

  gbar(bar, bid, tid, 1u, xcc);

  // ================= P3: tiled all-pairs suppressor detection =================
  {
    const int gwid = bid * 4 + wid;   // 0..1023
    for (int t = gwid; t < NPAIRS * BATCH; t += 1024) {
      const int b = t & 3;
      const int p = t >> 2;
      int tj = (int)((sqrtf(8.0f * (float)p + 1.0f) - 1.0f) * 0.5f);
      while ((tj + 1) * (tj + 2) / 2 <= p) ++tj;
      while (tj * (tj + 1) / 2 > p) --tj;
      int ti = p - tj * (tj + 1) / 2;
      int n = min((int)ctrs[b], MMAX);
      if (tj * 64 >= n) continue;   // uniform across wave

      int ii = ti * 64 + lane;
      float4 I = make_float4(0.f, 0.f, 0.f, 0.f);
      int ilv = -1;
      if (ii < n) {
        I = sboxes[(size_t)b * MMAX + ii];
        ilv = slev[(size_t)b * MMAX + ii];
      }
      int j = tj * 64 + lane;
      bool jv = (j < n);
      float4 J = make_float4(0.f, 0.f, 0.f, 0.f);
      int jl = -2;
      float aj = 0.0f;
      if (jv) {
        J = sboxes[(size_t)b * MMAX + j];
        jl = slev[(size_t)b * MMAX + j];
        aj = (J.z - J.x) * (J.w - J.y);
      }
      int imax = (ti == tj) ? lane : 64;  // diagonal: only i<j
      for (int k = 0; k < 64; ++k) {
        int   kl = __shfl(ilv, k, 64);
        float Ix = __shfl(I.x, k, 64);
        float Iy = __shfl(I.y, k, 64);
        float Iz = __shfl(I.z, k, 64);
        float Iw = __shfl(I.w, k, 64);
        if (!jv || k >= imax || kl != jl) continue;
        float xx1 = fmaxf(Ix, J.x), yy1 = fmaxf(Iy, J.y);
        float xx2 = fminf(Iz, J.z), yy2 = fminf(Iw, J.w);
        float inter = fmaxf(xx2 - xx1, 0.0f) * fmaxf(yy2 - yy1, 0.0f);
        float ai = (Iz - Ix) * (Iw - Iy);
        float iou = inter / fmaxf((ai + aj) - inter, 1e-6f);
        if (iou > NMS_T) {
          uint32_t s = atomicAdd(&cnt2[(size_t)b * MMAX + j], 1u);
          if (s < (uint32_t)KSUP) suplist[((size_t)b * MMAX + j) * KSUP + s] = ti * 64 + k;
          else atomicOr(&ctrs[8 + b], 1u);  // suppressor-list overflow -> fallback
        }
      }
    }
  }

  gbar(bar, bid, tid, 2u, xcc);

  // ================= P4: exact ordered resolution + output (blocks 0..3) =================
  if (bid < BATCH) {
    const int b = bid;
    int n = min((int)ctrs[b], MMAX);
    const int jb = tid * 8;   // 256 threads x 8 = MMAX
    uint32_t cj[8];
    uint32_t uf = 0, usum = 0;
#pragma unroll
    for (int k = 0; k < 8; ++k) {
      int j = jb + k;
      uint32_t c = (j < n) ? cnt2[(size_t)b * MMAX + j] : 0u;
      cj[k] = c;
      kept[j] = (j < n && c == 0u) ? 1 : 0;  // tri-state: 1=kept, 0=unresolved
      uint32_t u = (j < n && c > 0u) ? 1u : 0u;
      uf |= (u << k); usum += u;
    }
    uint32_t tot_unc;
    uint32_t base = blockscan(usum, wsum, tid, &tot_unc);
    {
      uint32_t p = base;
#pragma unroll
      for (int k = 0; k < 8; ++k) {
        if ((uf >> k) & 1u) {
          if (p < (uint32_t)UNC) {
            int j = jb + k;
            int m = (int)min(cj[k], (uint32_t)KSUP);
            unc[p] = (uint16_t)j; supn[p] = (uint8_t)m;
            for (int s = 0; s < m; ++s)
              supld[p][s] = suplist[((size_t)b * MMAX + j) * KSUP + s];
          }
          p++;
        }
      }
    }
    uint32_t nu32 = min(tot_unc, (uint32_t)UNC);
    // ---- parallel monotone sweeps: supplier kept => suppressed; all
    // suppliers suppressed => kept. Decisions are final when made, so
    // concurrent sweep reads are safe (state only moves 0 -> {1,2}).
    for (int sw = 0; sw < 3; ++sw) {
      __syncthreads();
      if (tid < (int)nu32) {
        int j = unc[tid];
        if (kept[j] == 0) {
          int m = (int)supn[tid];
          bool anyK = false, allS = true;
          for (int s = 0; s < m; ++s) {
            uint8_t st = kept[supld[tid][s]];
            anyK |= (st == 1); allS &= (st == 2);
          }
          if (anyK) kept[j] = 2;
          else if (allS) kept[j] = 1;
        }
      }
    }
    __syncthreads();
    // ---- order-preserving compaction of still-unresolved slots ----
    uint32_t isun = (tid < (int)nu32 && kept[unc[tid]] == 0) ? 1u : 0u;
    uint32_t nunr_tot;
    uint32_t upos = blockscan(isun, wsum, tid, &nunr_tot);
    if (isun) unr[upos] = (uint16_t)tid;
    __syncthreads();
    // ---- exact serial greedy over the few survivors (ascending rank) ----
    if (tid < 64) {
      int nr = (int)nunr_tot;
      for (int u2 = 0; u2 < nr; ++u2) {
        int u = unr[u2];
        int m = (int)supn[u];
        int pred = (tid < m) ? ((kept[supld[u][tid]] == 1) ? 1 : 0) : 0;
        unsigned long long bal = __ballot(pred);
        if (tid == 0) kept[unc[u]] = (bal == 0ULL) ? 1 : 2;
      }
    }
    __syncthreads();
    uint32_t kf = 0, ksum = 0;
#pragma unroll
    for (int k = 0; k < 8; ++k) {
      uint32_t kk = (kept[jb + k] == 1) ? 1u : 0u;
      kf |= (kk << k); ksum += kk;
    }
    uint32_t total;
    uint32_t pb = blockscan(ksum, wsum, tid, &total);
    {
      uint32_t p = pb;
#pragma unroll
      for (int k = 0; k < 8; ++k) {
        if ((kf >> k) & 1u) {
          if (p < (uint32_t)TOPN) {
            float4 bx = sboxes[(size_t)b * MMAX + jb + k];
            size_t o = ((size_t)b * TOPN + p) * 5;
            out[o] = (float)b; out[o+1] = bx.x; out[o+2] = bx.y; out[o+3] = bx.z; out[o+4] = bx.w;
          }
          p++;
        }
      }
    }
    for (int t = tid; t < TOPN; t += 256) {
      if ((uint32_t)t >= total) {
        size_t o = ((size_t)b * TOPN + t) * 5;
        out[o] = (float)b; out[o+1] = 0.0f; out[o+2] = 0.0f; out[o+3] = 0.0f; out[o+4] = 0.0f;
      }
    }

    bool needFB = (ctrs[8 + b] != 0u) || (total < (uint32_t)TOPN) || (tot_unc > (uint32_t)UNC);
    if (needFB) {
      // ---------- exact brute-force fallback (block-uniform path, 256 threads) ----------
      const float wmax = im_info[b * 3 + 1] - 1.0f;
      const float hmax = im_info[b * 3 + 0] - 1.0f;
      __syncthreads();  // order resolve-phase writes before overwrite
      float mx = 0.0f;
      for (int i = tid; i < NB; i += 256) {
        float x1, y1, x2, y2;
        decode_box(anchors4, deltas4, b, i, wmax, hmax, x1, y1, x2, y2);
        mx = fmaxf(mx, fmaxf(fmaxf(x1, y1), fmaxf(x2, y2)));
      }
      for (int o = 32; o > 0; o >>= 1) mx = fmaxf(mx, __shfl_xor(mx, o, 64));
      if ((tid & 63) == 0) fm[tid >> 6] = mx;
      __syncthreads();
      if (tid == 0) fm[0] = fmaxf(fmaxf(fm[0], fm[1]), fmaxf(fm[2], fm[3]));
      for (int i = tid; i < NB / 32; i += 256) mask[i] = 0u;
      __syncthreads();
      float max_c = fm[0] + 1.0f;
      for (int it = 0; it < TOPN; ++it) {
        float bv = -3e38f; int bi = 0x7fffffff;
        for (int i = tid; i < NB; i += 256) {
          bool sup = (mask[i >> 5] >> (i & 31)) & 1u;
          float v = sup ? NEGV : scores[(size_t)b * NB + i];
          if (v > bv || (v == bv && i < bi)) { bv = v; bi = i; }
        }
        rv[tid] = bv; ri[tid] = bi;
        __syncthreads();
        for (int s = 128; s > 0; s >>= 1) {
          if (tid < s) {
            float v2 = rv[tid + s]; int i2 = ri[tid + s];
            if (v2 > rv[tid] || (v2 == rv[tid] && i2 < ri[tid])) { rv[tid] = v2; ri[tid] = i2; }
          }
          __syncthreads();
        }
        int ii = ri[0]; float vv = rv[0];
        bool valid = vv > NEGV * 0.5f;
        if (!valid) {
          if (tid == 0) {
            size_t o = ((size_t)b * TOPN + it) * 5;
            out[o] = (float)b; out[o+1] = 0; out[o+2] = 0; out[o+3] = 0; out[o+4] = 0;
          }
          __syncthreads();
          continue;
        }
        float x1, y1, x2, y2;
        decode_box(anchors4, deltas4, b, ii, wmax, hmax, x1, y1, x2, y2);
        int lv = ids[ii];
        float off = (float)lv * max_c;
        float s0 = x1 + off, s1 = y1 + off, s2 = x2 + off, s3 = y2 + off;
        float a1 = (s2 - s0) * (s3 - s1);
        if (tid == 0) {
          size_t o = ((size_t)b * TOPN + it) * 5;
          out[o] = (float)b; out[o+1] = x1; out[o+2] = y1; out[o+3] = x2; out[o+4] = y2;
        }
        for (int j = tid; j < NB; j += 256) {
          if ((mask[j >> 5] >> (j & 31)) & 1u) continue;
          if (ids[j] != lv) continue;  // cross-level IoU exactly 0 under offset geometry
          float bx1, by1, bx2, by2;
          decode_box(anchors4, deltas4, b, j, wmax, hmax, bx1, by1, bx2, by2);
          float t0 = bx1 + off, t1 = by1 + off, t2 = bx2 + off, t3 = by2 + off;
          float xx1 = fmaxf(s0, t0), yy1 = fmaxf(s1, t1);
          float xx2 = fminf(s2, t2), yy2 = fminf(s3, t3);
          float inter = fmaxf(xx2 - xx1, 0.0f) * fmaxf(yy2 - yy1, 0.0f);
          float a2r = (t2 - t0) * (t3 - t1);
          float iou = inter / fmaxf(a1 + a2r - inter, 1e-6f);
          if (iou > NMS_T) atomicOr(&mask[j >> 5], 1u << (j & 31));
        }
        if (tid == 0) atomicOr(&mask[ii >> 5], 1u << (ii & 31));
        __syncthreads();
      }
    }
  }
}

extern "C" void kernel_launch(void* const* d_in, const int* in_sizes, int n_in,
                              void* d_out, int out_size, void* d_ws, size_t ws_size,
                              hipStream_t stream) {
  const float*  scores   = (const float*)d_in[0];
  const float4* deltas4  = (const float4*)d_in[1];
  const float4* anchors4 = (const float4*)d_in[2];
  const float*  im_info  = (const float*)d_in[3];
  const int*    ids      = (const int*)d_in[4];
  float* out = (float*)d_out;

  char* ws = (char*)d_ws;
  uint32_t*           ctrs     = (uint32_t*)ws;
  uint32_t*           cnt_blk  = (uint32_t*)(ws + OFF_CBLK);
  unsigned long long* keys_raw = (unsigned long long*)(ws + OFF_KRAW);
  float4*             sboxes   = (float4*)(ws + OFF_SBOX);
  int*                slev     = (int*)(ws + OFF_SLEV);
  uint32_t*           cnt2     = (uint32_t*)(ws + OFF_CNT2);
  int*                suplist  = (int*)(ws + OFF_SUP);
  uint32_t*           bar      = (uint32_t*)(ws + OFF_BAR);

  hipLaunchKernelGGL(k_init, dim3(1), dim3(64), 0, stream, bar);
  hipLaunchKernelGGL(k_fused, dim3(GRIDN), dim3(256), 0, stream,
                     scores, deltas4, anchors4, im_info, ids,
                     keys_raw, cnt_blk, ctrs, sboxes, slev, cnt2, suplist, bar, out);
}

// Round 5
// 112.941 us; speedup vs baseline: 1.8243x; 1.1149x over previous
//
#include <hip/hip_runtime.h>
#include <stdint.h>

#define NB     65536
#define BATCH  4
#define TOPN   1000
#define MMAX   2048
#define NTILE  (MMAX / 64)                 // 32
#define NPAIRS (NTILE * (NTILE + 1) / 2)   // 528
#define CAP    128                         // per-prep-block candidate region
#define KSUP   8
#define UNC    128
#define THRESH 0.974f
#define NEGV   (-1e9f)
#define NMS_T  0.7f
#define GRIDN  256                         // fused-kernel grid size

// ws layout (bytes):
//   ctrs u32[16]: [0..3]=n, [8..11]=fallback flag
//   barrier area at OFF_BAR: 25 u32 words spread 64B apart (word = line*16):
//     L0..15 arrival slots   L16 arrival root   L17..24 generation mirrors
#define OFF_CBLK   64
#define OFF_KRAW   1088
#define OFF_SBOX   263232
#define OFF_SLEV   394304
#define OFF_CNT2   427072
#define OFF_SUP    459840
#define OFF_BAR    721984                  // 64B-aligned; area = 1600 B

// ---- coherence-point (agent-scope, L2-bypassing) load/store helpers ----
// All cross-block arrays go through these, so grid barriers need NO cache
// maintenance (no buffer_wbl2 / buffer_inv tag walks).
__device__ __forceinline__ void st_u32(uint32_t* p, uint32_t v) {
  __hip_atomic_store(p, v, __ATOMIC_RELAXED, __HIP_MEMORY_SCOPE_AGENT);
}
__device__ __forceinline__ uint32_t ld_u32(const uint32_t* p) {
  return __hip_atomic_load((uint32_t*)p, __ATOMIC_RELAXED, __HIP_MEMORY_SCOPE_AGENT);
}
__device__ __forceinline__ void st_u64(unsigned long long* p, unsigned long long v) {
  __hip_atomic_store(p, v, __ATOMIC_RELAXED, __HIP_MEMORY_SCOPE_AGENT);
}
__device__ __forceinline__ unsigned long long ld_u64(const unsigned long long* p) {
  return __hip_atomic_load((unsigned long long*)p, __ATOMIC_RELAXED,
                           __HIP_MEMORY_SCOPE_AGENT);
}
__device__ __forceinline__ void st_f4(float4* p, float4 v) {
  union { float4 f; unsigned long long u[2]; } c; c.f = v;
  st_u64((unsigned long long*)p, c.u[0]);
  st_u64((unsigned long long*)p + 1, c.u[1]);
}
__device__ __forceinline__ float4 ld_f4(const float4* p) {
  union { float4 f; unsigned long long u[2]; } c;
  c.u[0] = ld_u64((const unsigned long long*)p);
  c.u[1] = ld_u64((const unsigned long long*)p + 1);
  return c.f;
}

__device__ __forceinline__ void decode_box(const float4* __restrict__ anchors4,
                                           const float4* __restrict__ deltas4,
                                           int b, int i, float wmax, float hmax,
                                           float& x1, float& y1, float& x2, float& y2) {
  float4 a = anchors4[i];
  float4 d = deltas4[(size_t)b * NB + i];
  float ws = a.z - a.x + 1.0f;
  float hs = a.w - a.y + 1.0f;
  float cx = a.x + 0.5f * ws;
  float cy = a.y + 0.5f * hs;
  float pcx = d.x * ws + cx;
  float pcy = d.y * hs + cy;
  float pw = expf(d.z) * ws;
  float ph = expf(d.w) * hs;
  x1 = pcx - 0.5f * pw; y1 = pcy - 0.5f * ph;
  x2 = pcx + 0.5f * pw; y2 = pcy + 0.5f * ph;
  x1 = fminf(fmaxf(x1, 0.0f), wmax);
  y1 = fminf(fmaxf(y1, 0.0f), hmax);
  x2 = fminf(fmaxf(x2, 0.0f), wmax);
  y2 = fminf(fmaxf(y2, 0.0f), hmax);
}

// block-wide exclusive scan, 256 threads (4 waves). wsum: u32[5].
__device__ __forceinline__ uint32_t blockscan(uint32_t v, volatile uint32_t* wsum,
                                              int tid, uint32_t* total) {
  __syncthreads();
  int lane = tid & 63, wid = tid >> 6;
  uint32_t x = v;
  for (int off = 1; off < 64; off <<= 1) {
    uint32_t u = __shfl_up(x, off, 64);
    if (lane >= off) x += u;
  }
  if (lane == 63) wsum[wid] = x;
  __syncthreads();
  if (tid == 0) {
    uint32_t run = 0;
    for (int w = 0; w < 4; ++w) { uint32_t t = wsum[w]; wsum[w] = run; run += t; }
    wsum[4] = run;
  }
  __syncthreads();
  *total = wsum[4];
  return x - v + wsum[wid];
}

// Flush-free decontended grid barrier. All 256 blocks co-resident (1/CU).
// All cross-block data moves through coherence-point accesses, so no L2
// writeback/invalidate is needed here: the compiler's s_waitcnt vmcnt(0)
// before s_barrier (entry __syncthreads) guarantees this block's coherent
// stores are globally visible before its arrival is counted.
__device__ __forceinline__ void gbar(uint32_t* bar, int bid, int tid, uint32_t g) {
  __syncthreads();
  if (tid == 0) {
    const uint32_t tgt = g + 1u;
    uint32_t* slot = bar + (bid & 15) * 16;
    uint32_t* root = bar + 16 * 16;
    uint32_t* mir  = bar + (17 + (bid & 7)) * 16;
    uint32_t a = __hip_atomic_fetch_add(slot, 1u, __ATOMIC_RELAXED, __HIP_MEMORY_SCOPE_AGENT);
    if (a == 15u) {                       // last arrival in this slot
      uint32_t r = __hip_atomic_fetch_add(root, 1u, __ATOMIC_RELAXED, __HIP_MEMORY_SCOPE_AGENT);
      if (r == 15u) {                     // last slot overall
        __hip_atomic_store(root, 0u, __ATOMIC_RELAXED, __HIP_MEMORY_SCOPE_AGENT);
        for (int s = 0; s < 16; ++s)
          __hip_atomic_store(bar + s * 16, 0u, __ATOMIC_RELAXED, __HIP_MEMORY_SCOPE_AGENT);
        asm volatile("s_waitcnt vmcnt(0)" ::: "memory");  // resets visible pre-release
        for (int m = 0; m < 8; ++m)
          __hip_atomic_fetch_add(bar + (17 + m) * 16, 1u, __ATOMIC_RELAXED,
                                 __HIP_MEMORY_SCOPE_AGENT);
      }
    }
    while (__hip_atomic_load(mir, __ATOMIC_RELAXED, __HIP_MEMORY_SCOPE_AGENT) < tgt)
      __builtin_amdgcn_s_sleep(4);
  }
  __syncthreads();
}

__global__ void k_init(uint32_t* bar) {
  if (threadIdx.x < 25)
    __hip_atomic_store(&bar[threadIdx.x * 16], 0u, __ATOMIC_RELAXED,
                       __HIP_MEMORY_SCOPE_AGENT);
}

// Fused pipeline: prep -> rank -> pairs -> out, separated by grid barriers.
__global__ __launch_bounds__(256) void k_fused(
    const float* __restrict__ scores, const float4* __restrict__ deltas4,
    const float4* __restrict__ anchors4, const float* __restrict__ im_info,
    const int* __restrict__ ids,
    unsigned long long* __restrict__ keys_raw, uint32_t* __restrict__ cnt_blk,
    uint32_t* ctrs, float4* __restrict__ sboxes, int* __restrict__ slev,
    uint32_t* __restrict__ cnt2, int* __restrict__ suplist,
    uint32_t* __restrict__ bar, float* __restrict__ out) {
  const int bid = blockIdx.x;
  const int tid = threadIdx.x;
  const int lane = tid & 63, wid = tid >> 6;

  // ---- shared memory (static; lifetimes separated by grid barriers) ----
  __shared__ uint32_t wsum[17];                 // P1 + P4 scans (uses [0..4])
  __shared__ unsigned long long sk[MMAX];       // P2: 16 KB
  __shared__ uint32_t scnt[64], sbs[64];        // P2
  __shared__ uint32_t psum[256];                // P2
  __shared__ uint32_t meta[2];                  // P2
  __shared__ uint8_t  kept[MMAX];               // P4: 0=unres 1=kept 2=supp
  __shared__ uint16_t unc[UNC];                 // P4
  __shared__ int      supld[UNC][KSUP];         // P4: 4 KB
  __shared__ uint8_t  supn[UNC];                // P4
  __shared__ uint16_t unr[UNC];                 // P4: unresolved-after-sweeps
  __shared__ uint32_t mask[NB / 32];            // P4 fallback: 8 KB
  __shared__ float    rv[256];                  // P4 fallback
  __shared__ int      ri[256];                  // P4 fallback
  __shared__ float    fm[4];                    // P4 fallback

  // ================= P1: score-threshold scan (all 256 blocks) =================
  {
    const int b = bid >> 6;        // 64 blocks / image
    const int blk = bid & 63;      // 1024 scores / block
    const float4* s4 = (const float4*)scores + (size_t)b * (NB / 4) + (size_t)blk * 256 + tid;
    float4 s = *s4;
    float sc4[4] = {s.x, s.y, s.z, s.w};
    uint32_t cmask = 0, ccount = 0;
#pragma unroll
    for (int k = 0; k < 4; ++k)
      if (sc4[k] >= THRESH) { cmask |= (1u << k); ccount++; }
    uint32_t total;
    uint32_t p = blockscan(ccount, wsum, tid, &total);
    if (tid == 0) st_u32(&cnt_blk[bid], total);  // TRUE count (P2 detects >CAP)
    unsigned long long* dst = keys_raw + (size_t)bid * CAP;
#pragma unroll
    for (int k = 0; k < 4; ++k) {
      if (cmask & (1u << k)) {
        if (p < (uint32_t)CAP) {
          int i = (blk << 10) + (tid << 2) + k;
          st_u64(&dst[p],
                 ((unsigned long long)(~__float_as_uint(sc4[k])) << 32) | (uint32_t)i);
        }
        p++;
      }
    }
  }

  gbar(bar, bid, tid, 0u);

  // ================= P2: compaction + rank + decode (blocks 0..127) =================
  if (bid < NTILE * BATCH) {
    const int b = bid >> 5;
    const int r = bid & 31;        // owns candidates [r*64, r*64+64)
    if (tid < 64) {
      uint32_t c = ld_u32(&cnt_blk[b * 64 + tid]);
      uint32_t cc = min(c, (uint32_t)CAP);
      scnt[tid] = cc;
      uint32_t x = cc;
      for (int off = 1; off < 64; off <<= 1) {
        uint32_t u = __shfl_up(x, off, 64);
        if (lane >= off) x += u;
      }
      sbs[tid] = x - cc;
      unsigned long long ov = __ballot(c > (uint32_t)CAP);
      if (tid == 63) { meta[0] = x; meta[1] = (ov != 0ULL) ? 1u : 0u; }
    }
    __syncthreads();
    uint32_t nsum = meta[0];
    int n = min((int)nsum, MMAX);
    uint32_t flag = meta[1] | ((nsum > (uint32_t)MMAX) ? 1u : 0u);
    if (r == 0 && tid == 0) {
      st_u32(&ctrs[b], (uint32_t)n);
      st_u32(&ctrs[8 + b], flag);
    }
    if (tid < 64) st_u32(&cnt2[(size_t)b * MMAX + r * 64 + tid], 0u);
    // compact: thread group of 4 per source block; 8-deep batched coherent loads
    {
      int k = tid >> 2, q = tid & 3;
      uint32_t cb = sbs[k], cc = scnt[k];
      const unsigned long long* src = keys_raw + ((size_t)b * 64 + k) * CAP;
      for (uint32_t o0 = q; o0 < cc; o0 += 32) {
        unsigned long long v[8];
#pragma unroll
        for (int u = 0; u < 8; ++u) {
          uint32_t o = o0 + 4u * u;
          if (o < cc) v[u] = ld_u64(&src[o]);
        }
#pragma unroll
        for (int u = 0; u < 8; ++u) {
          uint32_t o = o0 + 4u * u;
          uint32_t d = cb + o;
          if (o < cc && d < (uint32_t)MMAX) sk[d] = v[u];
        }
      }
    }
    for (int i = tid; i < MMAX; i += 256) if (i >= n) sk[i] = ~0ULL;
    __syncthreads();
    // rank my 64 candidates: each wave counts one 512-key window (broadcast reads)
    int c = r * 64 + lane;
    uint32_t partial = 0;
    if (c < n) {
      unsigned long long myk = sk[c];
      const ulonglong2* p2 = (const ulonglong2*)(sk + (size_t)wid * 512);
      for (int it = 0; it < 256; it += 4) {
        ulonglong2 a = p2[it], bq = p2[it + 1], cq = p2[it + 2], dq = p2[it + 3];
        partial += (uint32_t)(a.x < myk) + (uint32_t)(a.y < myk) +
                   (uint32_t)(bq.x < myk) + (uint32_t)(bq.y < myk) +
                   (uint32_t)(cq.x < myk) + (uint32_t)(cq.y < myk) +
                   (uint32_t)(dq.x < myk) + (uint32_t)(dq.y < myk);
      }
    }
    psum[wid * 64 + lane] = partial;
    __syncthreads();
    if (tid < 64) {
      int cc = r * 64 + tid;
      if (cc < n) {
        uint32_t rank = psum[tid] + psum[64 + tid] + psum[128 + tid] + psum[192 + tid];
        if (rank < (uint32_t)MMAX) {
          unsigned long long key = sk[cc];
          int i = (int)(uint32_t)key;
          float wmax = im_info[b * 3 + 1] - 1.0f;
          float hmax = im_info[b * 3 + 0] - 1.0f;
          float x1, y1, x2, y2;
          decode_box(anchors4, deltas4, b, i, wmax, hmax, x1, y1, x2, y2);
          st_f4(&sboxes[(size_t)b * MMAX + rank], make_float4(x1, y1, x2, y2));
          st_u32((uint32_t*)&slev[(size_t)b * MMAX + rank], (uint32_t)ids[i]);
        }
      }
    }
  }

  gbar(bar, bid, tid, 1u);

  // ================= P3: tiled all-pairs suppressor detection =================
  {
    const int gwid = bid * 4 + wid;   // 0..1023
    for (int t = gwid; t < NPAIRS * BATCH; t += 1024) {
      const int b = t & 3;
      const int p = t >> 2;
      int tj = (int)((sqrtf(8.0f * (float)p + 1.0f) - 1.0f) * 0.5f);
      while ((tj + 1) * (tj + 2) / 2 <= p) ++tj;
      while (tj * (tj + 1) / 2 > p) --tj;
      int ti = p - tj * (tj + 1) / 2;
      int n = min((int)ld_u32(&ctrs[b]), MMAX);
      if (tj * 64 >= n) continue;   // uniform across wave

      int ii = ti * 64 + lane;
      float4 I = make_float4(0.f, 0.f, 0.f, 0.f);
      int ilv = -1;
      if (ii < n) {
        I = ld_f4(&sboxes[(size_t)b * MMAX + ii]);
        ilv = (int)ld_u32((const uint32_t*)&slev[(size_t)b * MMAX + ii]);
      }
      int j = tj * 64 + lane;
      bool jv = (j < n);
      float4 J = make_float4(0.f, 0.f, 0.f, 0.f);
      int jl = -2;
      float aj = 0.0f;
      if (jv) {
        J = ld_f4(&sboxes[(size_t)b * MMAX + j]);
        jl = (int)ld_u32((const uint32_t*)&slev[(size_t)b * MMAX + j]);
        aj = (J.z - J.x) * (J.w - J.y);
      }
      int imax = (ti == tj) ? lane : 64;  // diagonal: only i<j
      for (int k = 0; k < 64; ++k) {
        int   kl = __shfl(ilv, k, 64);
        float Ix = __shfl(I.x, k, 64);
        float Iy = __shfl(I.y, k, 64);
        float Iz = __shfl(I.z, k, 64);
        float Iw = __shfl(I.w, k, 64);
        if (!jv || k >= imax || kl != jl) continue;
        float xx1 = fmaxf(Ix, J.x), yy1 = fmaxf(Iy, J.y);
        float xx2 = fminf(Iz, J.z), yy2 = fminf(Iw, J.w);
        float inter = fmaxf(xx2 - xx1, 0.0f) * fmaxf(yy2 - yy1, 0.0f);
        float ai = (Iz - Ix) * (Iw - Iy);
        float iou = inter / fmaxf((ai + aj) - inter, 1e-6f);
        if (iou > NMS_T) {
          uint32_t s = atomicAdd(&cnt2[(size_t)b * MMAX + j], 1u);
          if (s < (uint32_t)KSUP)
            st_u32((uint32_t*)&suplist[((size_t)b * MMAX + j) * KSUP + s],
                   (uint32_t)(ti * 64 + k));
          else atomicOr(&ctrs[8 + b], 1u);  // suppressor-list overflow -> fallback
        }
      }
    }
  }

  gbar(bar, bid, tid, 2u);

  // ================= P4: exact ordered resolution + output (blocks 0..3) =================
  if (bid < BATCH) {
    const int b = bid;
    int n = min((int)ld_u32(&ctrs[b]), MMAX);
    const int jb = tid * 8;   // 256 threads x 8 = MMAX
    uint32_t cj[8];
    uint32_t uf = 0, usum = 0;
#pragma unroll
    for (int k = 0; k < 8; ++k) {
      int j = jb + k;
      uint32_t c = (j < n) ? ld_u32(&cnt2[(size_t)b * MMAX + j]) : 0u;
      cj[k] = c;
      kept[j] = (j < n && c == 0u) ? 1 : 0;  // tri-state: 1=kept, 0=unresolved
      uint32_t u = (j < n && c > 0u) ? 1u : 0u;
      uf |= (u << k); usum += u;
    }
    uint32_t tot_unc;
    uint32_t base = blockscan(usum, wsum, tid, &tot_unc);
    {
      uint32_t p = base;
#pragma unroll
      for (int k = 0; k < 8; ++k) {
        if ((uf >> k) & 1u) {
          if (p < (uint32_t)UNC) {
            int j = jb + k;
            int m = (int)min(cj[k], (uint32_t)KSUP);
            unc[p] = (uint16_t)j; supn[p] = (uint8_t)m;
            for (int s = 0; s < m; ++s)
              supld[p][s] = (int)ld_u32((const uint32_t*)&suplist[((size_t)b * MMAX + j) * KSUP + s]);
          }
          p++;
        }
      }
    }
    uint32_t nu32 = min(tot_unc, (uint32_t)UNC);
    // ---- parallel monotone sweeps: supplier kept => suppressed; all
    // suppliers suppressed => kept. Decisions are final when made.
    for (int sw = 0; sw < 3; ++sw) {
      __syncthreads();
      if (tid < (int)nu32) {
        int j = unc[tid];
        if (kept[j] == 0) {
          int m = (int)supn[tid];
          bool anyK = false, allS = true;
          for (int s = 0; s < m; ++s) {
            uint8_t st = kept[supld[tid][s]];
            anyK |= (st == 1); allS &= (st == 2);
          }
          if (anyK) kept[j] = 2;
          else if (allS) kept[j] = 1;
        }
      }
    }
    __syncthreads();
    // ---- order-preserving compaction of still-unresolved slots ----
    uint32_t isun = (tid < (int)nu32 && kept[unc[tid]] == 0) ? 1u : 0u;
    uint32_t nunr_tot;
    uint32_t upos = blockscan(isun, wsum, tid, &nunr_tot);
    if (isun) unr[upos] = (uint16_t)tid;
    __syncthreads();
    // ---- exact serial greedy over the few survivors (ascending rank) ----
    if (tid < 64) {
      int nr = (int)nunr_tot;
      for (int u2 = 0; u2 < nr; ++u2) {
        int u = unr[u2];
        int m = (int)supn[u];
        int pred = (tid < m) ? ((kept[supld[u][tid]] == 1) ? 1 : 0) : 0;
        unsigned long long bal = __ballot(pred);
        if (tid == 0) kept[unc[u]] = (bal == 0ULL) ? 1 : 2;
      }
    }
    __syncthreads();
    uint32_t kf = 0, ksum = 0;
#pragma unroll
    for (int k = 0; k < 8; ++k) {
      uint32_t kk = (kept[jb + k] == 1) ? 1u : 0u;
      kf |= (kk << k); ksum += kk;
    }
    uint32_t total;
    uint32_t pb = blockscan(ksum, wsum, tid, &total);
    {
      uint32_t p = pb;
#pragma unroll
      for (int k = 0; k < 8; ++k) {
        if ((kf >> k) & 1u) {
          if (p < (uint32_t)TOPN) {
            float4 bx = ld_f4(&sboxes[(size_t)b * MMAX + jb + k]);
            size_t o = ((size_t)b * TOPN + p) * 5;
            out[o] = (float)b; out[o+1] = bx.x; out[o+2] = bx.y; out[o+3] = bx.z; out[o+4] = bx.w;
          }
          p++;
        }
      }
    }
    for (int t = tid; t < TOPN; t += 256) {
      if ((uint32_t)t >= total) {
        size_t o = ((size_t)b * TOPN + t) * 5;
        out[o] = (float)b; out[o+1] = 0.0f; out[o+2] = 0.0f; out[o+3] = 0.0f; out[o+4] = 0.0f;
      }
    }

    bool needFB = (ld_u32(&ctrs[8 + b]) != 0u) || (total < (uint32_t)TOPN) ||
                  (tot_unc > (uint32_t)UNC);
    if (needFB) {
      // ---------- exact brute-force fallback (block-uniform path, 256 threads) ----------
      const float wmax = im_info[b * 3 + 1] - 1.0f;
      const float hmax = im_info[b * 3 + 0] - 1.0f;
      __syncthreads();  // order resolve-phase writes before overwrite
      float mx = 0.0f;
      for (int i = tid; i < NB; i += 256) {
        float x1, y1, x2, y2;
        decode_box(anchors4, deltas4, b, i, wmax, hmax, x1, y1, x2, y2);
        mx = fmaxf(mx, fmaxf(fmaxf(x1, y1), fmaxf(x2, y2)));
      }
      for (int o = 32; o > 0; o >>= 1) mx = fmaxf(mx, __shfl_xor(mx, o, 64));
      if ((tid & 63) == 0) fm[tid >> 6] = mx;
      __syncthreads();
      if (tid == 0) fm[0] = fmaxf(fmaxf(fm[0], fm[1]), fmaxf(fm[2], fm[3]));
      for (int i = tid; i < NB / 32; i += 256) mask[i] = 0u;
      __syncthreads();
      float max_c = fm[0] + 1.0f;
      for (int it = 0; it < TOPN; ++it) {
        float bv = -3e38f; int bi = 0x7fffffff;
        for (int i = tid; i < NB; i += 256) {
          bool sup = (mask[i >> 5] >> (i & 31)) & 1u;
          float v = sup ? NEGV : scores[(size_t)b * NB + i];
          if (v > bv || (v == bv && i < bi)) { bv = v; bi = i; }
        }
        rv[tid] = bv; ri[tid] = bi;
        __syncthreads();
        for (int s = 128; s > 0; s >>= 1) {
          if (tid < s) {
            float v2 = rv[tid + s]; int i2 = ri[tid + s];
            if (v2 > rv[tid] || (v2 == rv[tid] && i2 < ri[tid])) { rv[tid] = v2; ri[tid] = i2; }
          }
          __syncthreads();
        }
        int ii = ri[0]; float vv = rv[0];
        bool valid = vv > NEGV * 0.5f;
        if (!valid) {
          if (tid == 0) {
            size_t o = ((size_t)b * TOPN + it) * 5;
            out[o] = (float)b; out[o+1] = 0; out[o+2] = 0; out[o+3] = 0; out[o+4] = 0;
          }
          __syncthreads();
          continue;
        }
        float x1, y1, x2, y2;
        decode_box(anchors4, deltas4, b, ii, wmax, hmax, x1, y1, x2, y2);
        int lv = ids[ii];
        float off = (float)lv * max_c;
        float s0 = x1 + off, s1 = y1 + off, s2 = x2 + off, s3 = y2 + off;
        float a1 = (s2 - s0) * (s3 - s1);
        if (tid == 0) {
          size_t o = ((size_t)b * TOPN + it) * 5;
          out[o] = (float)b; out[o+1] = x1; out[o+2] = y1; out[o+3] = x2; out[o+4] = y2;
        }
        for (int j = tid; j < NB; j += 256) {
          if ((mask[j >> 5] >> (j & 31)) & 1u) continue;
          if (ids[j] != lv) continue;  // cross-level IoU exactly 0 under offset geometry
          float bx1, by1, bx2, by2;
          decode_box(anchors4, deltas4, b, j, wmax, hmax, bx1, by1, bx2, by2);
          float t0 = bx1 + off, t1 = by1 + off, t2 = bx2 + off, t3 = by2 + off;
          float xx1 = fmaxf(s0, t0), yy1 = fmaxf(s1, t1);
          float xx2 = fminf(s2, t2), yy2 = fminf(s3, t3);
          float inter = fmaxf(xx2 - xx1, 0.0f) * fmaxf(yy2 - yy1, 0.0f);
          float a2r = (t2 - t0) * (t3 - t1);
          float iou = inter / fmaxf(a1 + a2r - inter, 1e-6f);
          if (iou > NMS_T) atomicOr(&mask[j >> 5], 1u << (j & 31));
        }
        if (tid == 0) atomicOr(&mask[ii >> 5], 1u << (ii & 31));
        __syncthreads();
      }
    }
  }
}

extern "C" void kernel_launch(void* const* d_in, const int* in_sizes, int n_in,
                              void* d_out, int out_size, void* d_ws, size_t ws_size,
                              hipStream_t stream) {
  const float*  scores   = (const float*)d_in[0];
  const float4* deltas4  = (const float4*)d_in[1];
  const float4* anchors4 = (const float4*)d_in[2];
  const float*  im_info  = (const float*)d_in[3];
  const int*    ids      = (const int*)d_in[4];
  float* out = (float*)d_out;

  char* ws = (char*)d_ws;
  uint32_t*           ctrs     = (uint32_t*)ws;
  uint32_t*           cnt_blk  = (uint32_t*)(ws + OFF_CBLK);
  unsigned long long* keys_raw = (unsigned long long*)(ws + OFF_KRAW);
  float4*             sboxes   = (float4*)(ws + OFF_SBOX);
  int*                slev     = (int*)(ws + OFF_SLEV);
  uint32_t*           cnt2     = (uint32_t*)(ws + OFF_CNT2);
  int*                suplist  = (int*)(ws + OFF_SUP);
  uint32_t*           bar      = (uint32_t*)(ws + OFF_BAR);

  hipLaunchKernelGGL(k_init, dim3(1), dim3(64), 0, stream, bar);
  hipLaunchKernelGGL(k_fused, dim3(GRIDN), dim3(256), 0, stream,
                     scores, deltas4, anchors4, im_info, ids,
                     keys_raw, cnt_blk, ctrs, sboxes, slev, cnt2, suplist, bar, out);
}